// Round 1
// 598.708 us; speedup vs baseline: 1.0055x; 1.0055x over previous
//
#include <hip/hip_runtime.h>
#include <math.h>
#include <stdint.h>

#define N_NODES 20000
#define M_PAD 20032            // 313 * 64
#define N_EDGES 320000
#define N_GRAPHS 64
#define DIN 128
#define H 256
#define POOL_W 768

typedef __attribute__((ext_vector_type(8))) short bf16x8;   // 8 bf16 = 4 VGPRs
typedef __attribute__((ext_vector_type(4))) float f32x4;
typedef _Float16 h2 __attribute__((ext_vector_type(2)));    // packed f16 pair (1 VGPR)

__device__ __forceinline__ unsigned short f2bf(float f) {
    unsigned u = __builtin_bit_cast(unsigned, f);
    u += 0x7FFFu + ((u >> 16) & 1u);          // round-to-nearest-even
    return (unsigned short)(u >> 16);
}
__device__ __forceinline__ float bf2f(unsigned short u) {
    return __builtin_bit_cast(float, (unsigned)u << 16);
}
__device__ __forceinline__ unsigned short f2h(float f) {
    const _Float16 h = (_Float16)f;
    return __builtin_bit_cast(unsigned short, h);
}

#if __has_builtin(__builtin_amdgcn_fdot2)
#define DOT2(a, b, c) __builtin_amdgcn_fdot2((a), (b), (c), false)
#else
__device__ __forceinline__ float dot2_fallback(h2 a, h2 b, float c) {
    return fmaf((float)a.x, (float)b.x, fmaf((float)a.y, (float)b.y, c));
}
#define DOT2(a, b, c) dot2_fallback((a), (b), (c))
#endif

// ---------------------------------------------------------------------------
// Batched converts + zero jobs: 13 jobs, one launch.
// mode 0: fp32 -> bf16   mode 1: fp32 -> f16   mode 2: zero fill
// ---------------------------------------------------------------------------
struct CvtJob  { const float* s; unsigned short* d; int n4; int mode; };
struct CvtJobs { CvtJob j[13]; };

__global__ __launch_bounds__(256) void cvt_all(CvtJobs jobs)
{
    const CvtJob J = jobs.j[blockIdx.y];
    if (J.mode == 2) {
        const ushort4 z = {0, 0, 0, 0};
        for (int i = blockIdx.x * 256 + threadIdx.x; i < J.n4; i += gridDim.x * 256)
            ((ushort4*)J.d)[i] = z;
        return;
    }
    if (J.mode == 1) {
        for (int i = blockIdx.x * 256 + threadIdx.x; i < J.n4; i += gridDim.x * 256) {
            const float4 v = ((const float4*)J.s)[i];
            ushort4 r;
            r.x = f2h(v.x); r.y = f2h(v.y); r.z = f2h(v.z); r.w = f2h(v.w);
            ((ushort4*)J.d)[i] = r;
        }
        return;
    }
    for (int i = blockIdx.x * 256 + threadIdx.x; i < J.n4; i += gridDim.x * 256) {
        const float4 v = ((const float4*)J.s)[i];
        ushort4 r;
        r.x = f2bf(v.x); r.y = f2bf(v.y); r.z = f2bf(v.z); r.w = f2bf(v.w);
        ((ushort4*)J.d)[i] = r;
    }
}

// ---------------------------------------------------------------------------
// CSR build
// ---------------------------------------------------------------------------
__global__ __launch_bounds__(256) void hist_kernel(const int* __restrict__ dst,
                                                   int* __restrict__ deg)
{
    const int i = blockIdx.x * 256 + threadIdx.x;
    if (i < N_EDGES) atomicAdd(deg + dst[i], 1);
}

// shfl scan; writes off and cursor; tail threads also compute graph starts
__global__ __launch_bounds__(1024) void scan_kernel(const int* __restrict__ deg,
                                                    int* __restrict__ off,
                                                    int* __restrict__ cur,
                                                    const int* __restrict__ batch,
                                                    int* __restrict__ start)
{
    __shared__ int wsum[16];
    __shared__ int carry;
    const int tid = threadIdx.x, wave = tid >> 6, lane = tid & 63;
    if (tid == 0) carry = 0;
    __syncthreads();
    for (int base = 0; base < N_NODES; base += 1024) {
        const int i = base + tid;
        const int v = (i < N_NODES) ? deg[i] : 0;
        int s = v;
#pragma unroll
        for (int d = 1; d < 64; d <<= 1) {
            const int t = __shfl_up(s, d);
            if (lane >= d) s += t;
        }
        if (lane == 63) wsum[wave] = s;
        __syncthreads();
        if (wave == 0) {
            int t = (lane < 16) ? wsum[lane] : 0;
#pragma unroll
            for (int d = 1; d < 16; d <<= 1) {
                const int u = __shfl_up(t, d);
                if (lane >= d) t += u;
            }
            if (lane < 16) wsum[lane] = t;
        }
        __syncthreads();
        const int wbase = (wave == 0) ? 0 : wsum[wave - 1];
        if (i < N_NODES) {
            const int o = carry + wbase + s - v;
            off[i] = o;
            cur[i] = o;
        }
        const int tot = wsum[15];
        __syncthreads();
        if (tid == 0) carry += tot;
        __syncthreads();
    }
    if (tid == 0) off[N_NODES] = carry;

    // graph boundaries (batch is sorted)
    if (tid <= N_GRAPHS) {
        if (tid == N_GRAPHS) { start[N_GRAPHS] = N_NODES; }
        else {
            int lo = 0, hi = N_NODES;
            while (lo < hi) { const int mid = (lo + hi) >> 1; if (batch[mid] < tid) lo = mid + 1; else hi = mid; }
            start[tid] = lo;
        }
    }
}

// light scatter: dst-sorted (src, eid) pairs only — 2.5 MB
__global__ __launch_bounds__(256) void scatter_kernel(
    const int* __restrict__ src, const int* __restrict__ dst,
    int* __restrict__ cursor, int2* __restrict__ sidx)
{
    const int e = blockIdx.x * 256 + threadIdx.x;
    if (e < N_EDGES) {
        const int p = atomicAdd(cursor + dst[e], 1);
        sidx[p] = make_int2(src[e], e);
    }
}

// ---------------------------------------------------------------------------
// agg3 v2 — same node/wave decomposition as the proven R5 kernel, but the
// per-edge load path is rebuilt around the rocprof evidence (VGPR=44/SGPR=80,
// VALUBusy 46%): the readfirstlane'd addresses were scalarized into SMEM
// chains whose out-of-order returns force lgkmcnt(0) drains, serializing the
// prefetch. Changes:
//   1. divergence-injected VECTOR loads (vmcnt, in-order, pipelinable)
//   2. sidx resolved 2 iterations ahead (breaks the sidx->ea address dep)
//   3. edge MLP in packed-f16 v_dot2_f32_f16: half the regs, half the VALU;
//      weights pinned in VGPRs via empty asm so they cannot be re-sunk.
// out[v] = bf16( x[v] + sum_e relu(x[src] + ea@We.T + be) )
// ---------------------------------------------------------------------------
template<int IN>
__global__ __launch_bounds__(256, 4) void agg3(
    const unsigned short* __restrict__ xb,   // [M_PAD, IN] bf16
    const unsigned short* __restrict__ eah,  // [E,16] f16 (original edge order)
    const int2* __restrict__ sidx,           // (src, eid) sorted by dst
    const int* __restrict__ off,             // [N+1]
    const unsigned short* __restrict__ Weh,  // [IN,16] f16
    const float* __restrict__ be,
    unsigned short* __restrict__ out)        // [M_PAD, IN] bf16
{
    constexpr int CPL = IN / 64;             // 2 (layer1) or 4
    const int lane = threadIdx.x & 63;
    const int node = blockIdx.x * 4 + (threadIdx.x >> 6);
    if (node >= N_NODES) return;
    const int c0 = lane * CPL;
    const int zd = __builtin_amdgcn_mbcnt_lo(0u, 0u);   // divergent zero: defeats SMEM scalarization

    h2 w[CPL][8];
    float bias[CPL], acc[CPL];
#pragma unroll
    for (int j = 0; j < CPL; ++j) {
        bias[j] = be[c0 + j];
        acc[j]  = 0.0f;
        const h2* wr = (const h2*)(Weh + (size_t)(c0 + j) * 16);
#pragma unroll
        for (int kk = 0; kk < 8; ++kk) w[j][kk] = wr[kk];
    }
    // pin weights in VGPRs (opaque def: cannot be rematerialized by reloading)
#pragma unroll
    for (int j = 0; j < CPL; ++j)
#pragma unroll
        for (int kk = 0; kk < 8; ++kk) {
            float t = __builtin_bit_cast(float, w[j][kk]);
            asm volatile("" : "+v"(t));
            w[j][kk] = __builtin_bit_cast(h2, t);
        }

    const int p0 = __builtin_amdgcn_readfirstlane(off[node]);
    const int p1 = __builtin_amdgcn_readfirstlane(off[node + 1]);

    h2 en[8];
    ushort4 xn = {0, 0, 0, 0};
    int sN = 0, eN = 0;                      // ids for edge p+1 (VGPRs)
    if (p0 < p1) {
        const int2 se0 = sidx[p0 + zd];
        const h2* er = (const h2*)(eah + se0.y * 16);
#pragma unroll
        for (int kk = 0; kk < 8; ++kk) en[kk] = er[kk];
        const int xoff = se0.x * IN + c0;
        if (CPL == 4) xn = *(const ushort4*)(xb + xoff);
        else { const ushort2 t2 = *(const ushort2*)(xb + xoff); xn.x = t2.x; xn.y = t2.y; }
        if (p0 + 1 < p1) {
            const int2 se1 = sidx[p0 + 1 + zd];
            sN = se1.x; eN = se1.y;
        }
    }

    for (int p = p0; p < p1; ++p) {
        // issue sidx[p+2] — consumed next iteration (address dep broken)
        int sF = 0, eF = 0;
        if (p + 2 < p1) {
            const int2 se = sidx[p + 2 + zd];
            sF = se.x; eF = se.y;
        }
        // issue data loads for edge p+1 (addresses already resolved)
        h2 enN[8];
        ushort4 xnN;
        if (p + 1 < p1) {
            const h2* er = (const h2*)(eah + eN * 16);
#pragma unroll
            for (int kk = 0; kk < 8; ++kk) enN[kk] = er[kk];
            const int xoff = sN * IN + c0;
            if (CPL == 4) xnN = *(const ushort4*)(xb + xoff);
            else { const ushort2 t2 = *(const ushort2*)(xb + xoff); xnN.x = t2.x; xnN.y = t2.y; }
        }
        // compute on current edge (f16 dot2, fp32 accumulate)
        float m[CPL];
#pragma unroll
        for (int j = 0; j < CPL; ++j) m[j] = bias[j];
#pragma unroll
        for (int kk = 0; kk < 8; ++kk)
#pragma unroll
            for (int j = 0; j < CPL; ++j) m[j] = DOT2(en[kk], w[j][kk], m[j]);
#pragma unroll
        for (int j = 0; j < CPL; ++j) {
            const float v = m[j] + bf2f((&xn.x)[j]);
            acc[j] += fmaxf(v, 0.0f);
        }
        // rotate pipeline state
        if (p + 1 < p1) {
#pragma unroll
            for (int kk = 0; kk < 8; ++kk) en[kk] = enN[kk];
            xn = xnN; sN = sF; eN = eF;
        }
    }

    if (CPL == 4) {
        const ushort4 xs = *(const ushort4*)(xb + (size_t)node * IN + c0);
        ushort4 o;
#pragma unroll
        for (int j = 0; j < 4; ++j) (&o.x)[j] = f2bf(bf2f((&xs.x)[j]) + acc[j]);
        *(ushort4*)(out + (size_t)node * IN + c0) = o;
    } else {
        const ushort2 xs = *(const ushort2*)(xb + (size_t)node * IN + c0);
        ushort2 o;
        o.x = f2bf(bf2f(xs.x) + acc[0]);
        o.y = f2bf(bf2f(xs.y) + acc[1]);
        *(ushort2*)(out + (size_t)node * IN + c0) = o;
    }
}

// ---------------------------------------------------------------------------
// B-in-register streaming GEMM v2 (best measured config, R9):
// grid (313,2), 4 waves/block, wave owns 32 cols with K resident in regs;
// 4 chunks of 16 rows with 2-deep prefetch. No LDS, no barriers.
// EPI 0: BN(eval)+relu -> bf16 (all rows)   EPI 1: bias+relu (rows < N)
// ---------------------------------------------------------------------------
template<int K, int EPI>
__global__ __launch_bounds__(256) void gemm_breg2(
    const unsigned short* __restrict__ A,    // [M_PAD, K]
    const unsigned short* __restrict__ W,    // [256, K]
    const float* __restrict__ bias,
    const float* __restrict__ gsc, const float* __restrict__ bsh,
    unsigned short* __restrict__ out)        // [M_PAD, 256]
{
    constexpr int KC = K / 32;               // 4 or 8 k-chunks
    const int w = threadIdx.x >> 6, lane = threadIdx.x & 63;
    const int lm = lane & 15, lq = lane >> 4;
    const int n0 = (blockIdx.y * 4 + w) * 32;
    const int m0 = blockIdx.x * 64;

    // B resident in registers
    bf16x8 B0[KC], B1[KC];
    {
        const unsigned short* Wp0 = W + (size_t)(n0 + lm) * K + lq * 8;
        const unsigned short* Wp1 = W + (size_t)(n0 + 16 + lm) * K + lq * 8;
#pragma unroll
        for (int c = 0; c < KC; ++c) {
            B0[c] = *(const bf16x8*)(Wp0 + c * 32);
            B1[c] = *(const bf16x8*)(Wp1 + c * 32);
        }
    }

    const float inv = rsqrtf(1.0f + 1e-5f);
    const float bc0 = bias[n0 + lm],      bc1 = bias[n0 + 16 + lm];
    const float gc0 = (EPI == 0) ? gsc[n0 + lm]      : 0.0f;
    const float gc1 = (EPI == 0) ? gsc[n0 + 16 + lm] : 0.0f;
    const float sc0 = (EPI == 0) ? bsh[n0 + lm]      : 0.0f;
    const float sc1 = (EPI == 0) ? bsh[n0 + 16 + lm] : 0.0f;

    bf16x8 aC[KC], aN[KC];
    {
        const unsigned short* Ap = A + (size_t)(m0 + lm) * K + lq * 8;
#pragma unroll
        for (int c = 0; c < KC; ++c) aC[c] = *(const bf16x8*)(Ap + c * 32);
    }

#pragma unroll
    for (int ch = 0; ch < 4; ++ch) {
        if (ch < 3) {
            const unsigned short* Ap = A + (size_t)(m0 + (ch + 1) * 16 + lm) * K + lq * 8;
#pragma unroll
            for (int c = 0; c < KC; ++c) aN[c] = *(const bf16x8*)(Ap + c * 32);
        }

        f32x4 acc0 = (f32x4){0.f, 0.f, 0.f, 0.f};
        f32x4 acc1 = (f32x4){0.f, 0.f, 0.f, 0.f};
#pragma unroll
        for (int c = 0; c < KC; ++c) {
            acc0 = __builtin_amdgcn_mfma_f32_16x16x32_bf16(aC[c], B0[c], acc0, 0, 0, 0);
            acc1 = __builtin_amdgcn_mfma_f32_16x16x32_bf16(aC[c], B1[c], acc1, 0, 0, 0);
        }

        const int mr = m0 + ch * 16;
#pragma unroll
        for (int r = 0; r < 4; ++r) {
            const int row = mr + lq * 4 + r;
            if (EPI == 1 && row >= N_NODES) continue;
            float v0 = acc0[r] + bc0;
            float v1 = acc1[r] + bc1;
            if (EPI == 0) {
                v0 = fmaxf(v0 * inv * gc0 + sc0, 0.0f);
                v1 = fmaxf(v1 * inv * gc1 + sc1, 0.0f);
            } else {
                v0 = fmaxf(v0, 0.0f);
                v1 = fmaxf(v1, 0.0f);
            }
            out[(size_t)row * H + n0 + lm]      = f2bf(v0);
            out[(size_t)row * H + n0 + 16 + lm] = f2bf(v1);
        }

#pragma unroll
        for (int c = 0; c < KC; ++c) aC[c] = aN[c];
    }
}

// ---------------------------------------------------------------------------
// Parallel mean-pool: grid (192, RSPLIT). Block (g, layer, chunk) reduces
// ~rows/RSPLIT rows and atomicAdds one partial per column into pool.
// ---------------------------------------------------------------------------
#define RSPLIT 6
__global__ __launch_bounds__(256) void pool2(
    const unsigned short* __restrict__ h1, const unsigned short* __restrict__ h2,
    const unsigned short* __restrict__ h3, const int* __restrict__ start,
    float* __restrict__ pool)
{
    const int g = blockIdx.x & 63, layer = blockIdx.x >> 6;
    const unsigned short* h = (layer == 0) ? h1 : (layer == 1) ? h2 : h3;
    const int r0 = start[g], r1 = start[g + 1];
    const int nr = r1 - r0;
    if (nr <= 0) return;
    const int chunk = (nr + RSPLIT - 1) / RSPLIT;
    const int rs = r0 + blockIdx.y * chunk;
    const int re = (rs + chunk < r1) ? rs + chunk : r1;
    if (rs >= re) return;

    const int c = threadIdx.x;
    float s0 = 0.f, s1 = 0.f, s2 = 0.f, s3 = 0.f;
    int r = rs;
    for (; r + 4 <= re; r += 4) {
        s0 += bf2f(h[(size_t)(r + 0) * H + c]);
        s1 += bf2f(h[(size_t)(r + 1) * H + c]);
        s2 += bf2f(h[(size_t)(r + 2) * H + c]);
        s3 += bf2f(h[(size_t)(r + 3) * H + c]);
    }
    for (; r < re; ++r) s0 += bf2f(h[(size_t)r * H + c]);
    atomicAdd(&pool[(size_t)g * POOL_W + layer * 256 + c], s0 + s1 + s2 + s3);
}

// ---------------------------------------------------------------------------
// FC head: one block per graph; pool is pre-summed (divide by count here).
// ---------------------------------------------------------------------------
__global__ __launch_bounds__(256) void final_kernel(
    const float* __restrict__ pool, const int* __restrict__ start,
    const float* __restrict__ L1w, const float* __restrict__ L1b,
    const float* __restrict__ L2w, const float* __restrict__ L2b,
    float* __restrict__ out)
{
    const int g = blockIdx.x;
    __shared__ float p[POOL_W];
    __shared__ float f1[POOL_W];
    __shared__ float red[4];

    const float rc = 1.0f / fmaxf((float)(start[g + 1] - start[g]), 1.0f);
    for (int i = threadIdx.x; i < POOL_W; i += 256)
        p[i] = pool[(size_t)g * POOL_W + i] * rc;
    __syncthreads();

    for (int r = 0; r < 3; ++r) {
        const int o = r * 256 + threadIdx.x;
        float acc = L1b[o];
        const float4* wrow = (const float4*)(L1w + (size_t)o * POOL_W);
        for (int k4 = 0; k4 < POOL_W / 4; ++k4) {
            const float4 w4 = wrow[k4];
            acc += w4.x * p[k4 * 4 + 0] + w4.y * p[k4 * 4 + 1]
                 + w4.z * p[k4 * 4 + 2] + w4.w * p[k4 * 4 + 3];
        }
        f1[o] = fmaxf(acc, 0.0f);
    }
    __syncthreads();

    float part = 0.0f;
    for (int i = threadIdx.x; i < POOL_W; i += 256) part += f1[i] * L2w[i];
#pragma unroll
    for (int off = 32; off > 0; off >>= 1) part += __shfl_down(part, off);
    if ((threadIdx.x & 63) == 0) red[threadIdx.x >> 6] = part;
    __syncthreads();
    if (threadIdx.x == 0) {
        const float s = red[0] + red[1] + red[2] + red[3] + L2b[0];
        out[g] = 1.0f / (1.0f + expf(-s));
    }
}

// ---------------------------------------------------------------------------
extern "C" void kernel_launch(void* const* d_in, const int* in_sizes, int n_in,
                              void* d_out, int out_size, void* d_ws, size_t ws_size,
                              hipStream_t stream)
{
    const float* x     = (const float*)d_in[0];
    const float* ea    = (const float*)d_in[1];
    const int*   src   = (const int*)d_in[2];
    const int*   dst   = (const int*)d_in[3];
    const int*   batch = (const int*)d_in[4];

    const float* We[3]; const float* be[3]; const float* Wa[3]; const float* ba[3];
    const float* gg[3]; const float* bt[3]; const float* Wb[3]; const float* bb[3];
    for (int l = 0; l < 3; ++l) {
        const int o = 5 + 8 * l;
        We[l] = (const float*)d_in[o + 0]; be[l] = (const float*)d_in[o + 1];
        Wa[l] = (const float*)d_in[o + 2]; ba[l] = (const float*)d_in[o + 3];
        gg[l] = (const float*)d_in[o + 4]; bt[l] = (const float*)d_in[o + 5];
        Wb[l] = (const float*)d_in[o + 6]; bb[l] = (const float*)d_in[o + 7];
    }
    const float* L1w = (const float*)d_in[29];
    const float* L1b = (const float*)d_in[30];
    const float* L2w = (const float*)d_in[31];
    const float* L2b = (const float*)d_in[32];

    // ---- workspace layout ----
    float* pool   = (float*)d_ws;                              // 64*768
    int*   deg    = (int*)(pool + (size_t)N_GRAPHS * POOL_W);  // N
    int*   off    = deg + N_NODES;                             // N+1
    int*   cursor = off + N_NODES + 1;                         // N
    int*   start  = cursor + N_NODES;                          // 72
    int2*  sidx   = (int2*)((((uintptr_t)(start + 72)) + 15) & ~(uintptr_t)15);  // E
    unsigned short* xb = (unsigned short*)((((uintptr_t)(sidx + N_EDGES)) + 15) & ~(uintptr_t)15);
    unsigned short* u  = xb + (size_t)M_PAD * DIN;             // [M_PAD,256] (layer1 uses 128)
    unsigned short* tT = u  + (size_t)M_PAD * H;               // [M_PAD,256] intermediate
    unsigned short* h1 = tT + (size_t)M_PAD * H;
    unsigned short* h2 = h1 + (size_t)M_PAD * H;
    unsigned short* h3 = h2 + (size_t)M_PAD * H;
    unsigned short* wbf[6];
    wbf[0] = h3 + (size_t)M_PAD * H;                           // Wa1 [256,128]
    wbf[1] = wbf[0] + H * DIN;
    for (int i = 2; i < 6; ++i) wbf[i] = wbf[i - 1] + H * H;
    unsigned short* eah = wbf[5] + H * H;                      // [E,16] f16
    unsigned short* weh[3];
    weh[0] = eah + (size_t)N_EDGES * 16;                       // We1 [128,16] f16
    weh[1] = weh[0] + DIN * 16;                                // We2 [256,16] f16
    weh[2] = weh[1] + H * 16;                                  // We3 [256,16] f16

    // batched converts + deg/pool zeroing in one launch (13 jobs)
    CvtJobs jobs;
    jobs.j[0]  = { x,       xb,                    N_NODES * DIN / 4,       0 };
    jobs.j[1]  = { Wa[0],   wbf[0],                H * DIN / 4,             0 };
    jobs.j[2]  = { Wb[0],   wbf[1],                H * H / 4,               0 };
    jobs.j[3]  = { Wa[1],   wbf[2],                H * H / 4,               0 };
    jobs.j[4]  = { Wb[1],   wbf[3],                H * H / 4,               0 };
    jobs.j[5]  = { Wa[2],   wbf[4],                H * H / 4,               0 };
    jobs.j[6]  = { Wb[2],   wbf[5],                H * H / 4,               0 };
    jobs.j[7]  = { nullptr, (unsigned short*)deg,  N_NODES * 4 / 8,         2 };  // zero N ints
    jobs.j[8]  = { nullptr, (unsigned short*)pool, N_GRAPHS * POOL_W * 4 / 8, 2 };// zero pool
    jobs.j[9]  = { ea,      eah,                   N_EDGES * 16 / 4,        1 };  // ea -> f16
    jobs.j[10] = { We[0],   weh[0],                DIN * 16 / 4,            1 };
    jobs.j[11] = { We[1],   weh[1],                H * 16 / 4,              1 };
    jobs.j[12] = { We[2],   weh[2],                H * 16 / 4,              1 };
    cvt_all<<<dim3(320, 13), 256, 0, stream>>>(jobs);

    // CSR + graph boundaries
    hist_kernel<<<(N_EDGES + 255) / 256, 256, 0, stream>>>(dst, deg);
    scan_kernel<<<1, 1024, 0, stream>>>(deg, off, cursor, batch, start);
    scatter_kernel<<<(N_EDGES + 255) / 256, 256, 0, stream>>>(src, dst, cursor, sidx);

    const int  agrid = (N_NODES + 3) / 4;       // agg3: 1 node/wave
    const dim3 ggrid(M_PAD / 64, 2);            // (313, 2)

    // ---- layer 1 (in=128) ----
    agg3<DIN><<<agrid, 256, 0, stream>>>(xb, eah, sidx, off, weh[0], be[0], u);
    gemm_breg2<DIN, 0><<<ggrid, 256, 0, stream>>>(u, wbf[0], ba[0], gg[0], bt[0], tT);
    gemm_breg2<H,   1><<<ggrid, 256, 0, stream>>>(tT, wbf[1], bb[0], nullptr, nullptr, h1);
    // ---- layer 2 ----
    agg3<H><<<agrid, 256, 0, stream>>>(h1, eah, sidx, off, weh[1], be[1], u);
    gemm_breg2<H, 0><<<ggrid, 256, 0, stream>>>(u, wbf[2], ba[1], gg[1], bt[1], tT);
    gemm_breg2<H, 1><<<ggrid, 256, 0, stream>>>(tT, wbf[3], bb[1], nullptr, nullptr, h2);
    // ---- layer 3 ----
    agg3<H><<<agrid, 256, 0, stream>>>(h2, eah, sidx, off, weh[2], be[2], u);
    gemm_breg2<H, 0><<<ggrid, 256, 0, stream>>>(u, wbf[4], ba[2], gg[2], bt[2], tT);
    gemm_breg2<H, 1><<<ggrid, 256, 0, stream>>>(tT, wbf[5], bb[2], nullptr, nullptr, h3);

    // parallel mean-pool + head
    pool2<<<dim3(3 * N_GRAPHS, RSPLIT), 256, 0, stream>>>(h1, h2, h3, start, pool);
    final_kernel<<<N_GRAPHS, 256, 0, stream>>>(pool, start, L1w, L1b, L2w, L2b, (float*)d_out);
}

// Round 2
// 564.153 us; speedup vs baseline: 1.0671x; 1.0613x over previous
//
#include <hip/hip_runtime.h>
#include <math.h>
#include <stdint.h>

#define N_NODES 20000
#define M_PAD 20032            // 313 * 64
#define N_EDGES 320000
#define N_GRAPHS 64
#define DIN 128
#define H 256
#define POOL_W 768

typedef __attribute__((ext_vector_type(8))) short bf16x8;   // 8 bf16 = 4 VGPRs
typedef __attribute__((ext_vector_type(4))) float f32x4;
typedef __attribute__((ext_vector_type(4))) unsigned int u32x4;
typedef __attribute__((ext_vector_type(2))) unsigned int u32x2;
typedef _Float16 h2 __attribute__((ext_vector_type(2)));    // packed f16 pair (1 VGPR)

__device__ __forceinline__ unsigned short f2bf(float f) {
    unsigned u = __builtin_bit_cast(unsigned, f);
    u += 0x7FFFu + ((u >> 16) & 1u);          // round-to-nearest-even
    return (unsigned short)(u >> 16);
}
__device__ __forceinline__ float bf2f(unsigned short u) {
    return __builtin_bit_cast(float, (unsigned)u << 16);
}
__device__ __forceinline__ unsigned short f2h(float f) {
    const _Float16 h = (_Float16)f;
    return __builtin_bit_cast(unsigned short, h);
}

#if __has_builtin(__builtin_amdgcn_fdot2)
#define DOT2(a, b, c) __builtin_amdgcn_fdot2((a), (b), (c), false)
#else
__device__ __forceinline__ float dot2_fallback(h2 a, h2 b, float c) {
    return fmaf((float)a.x, (float)b.x, fmaf((float)a.y, (float)b.y, c));
}
#define DOT2(a, b, c) dot2_fallback((a), (b), (c))
#endif

// ---------------------------------------------------------------------------
// Batched converts + zero jobs: 13 jobs, one launch.
// mode 0: fp32 -> bf16   mode 1: fp32 -> f16   mode 2: zero fill
// ---------------------------------------------------------------------------
struct CvtJob  { const float* s; unsigned short* d; int n4; int mode; };
struct CvtJobs { CvtJob j[13]; };

__global__ __launch_bounds__(256) void cvt_all(CvtJobs jobs)
{
    const CvtJob J = jobs.j[blockIdx.y];
    if (J.mode == 2) {
        const ushort4 z = {0, 0, 0, 0};
        for (int i = blockIdx.x * 256 + threadIdx.x; i < J.n4; i += gridDim.x * 256)
            ((ushort4*)J.d)[i] = z;
        return;
    }
    if (J.mode == 1) {
        for (int i = blockIdx.x * 256 + threadIdx.x; i < J.n4; i += gridDim.x * 256) {
            const float4 v = ((const float4*)J.s)[i];
            ushort4 r;
            r.x = f2h(v.x); r.y = f2h(v.y); r.z = f2h(v.z); r.w = f2h(v.w);
            ((ushort4*)J.d)[i] = r;
        }
        return;
    }
    for (int i = blockIdx.x * 256 + threadIdx.x; i < J.n4; i += gridDim.x * 256) {
        const float4 v = ((const float4*)J.s)[i];
        ushort4 r;
        r.x = f2bf(v.x); r.y = f2bf(v.y); r.z = f2bf(v.z); r.w = f2bf(v.w);
        ((ushort4*)J.d)[i] = r;
    }
}

// ---------------------------------------------------------------------------
// CSR build
// ---------------------------------------------------------------------------
__global__ __launch_bounds__(256) void hist_kernel(const int* __restrict__ dst,
                                                   int* __restrict__ deg)
{
    const int i = blockIdx.x * 256 + threadIdx.x;
    if (i < N_EDGES) atomicAdd(deg + dst[i], 1);
}

// shfl scan; writes off and cursor; tail threads also compute graph starts
__global__ __launch_bounds__(1024) void scan_kernel(const int* __restrict__ deg,
                                                    int* __restrict__ off,
                                                    int* __restrict__ cur,
                                                    const int* __restrict__ batch,
                                                    int* __restrict__ start)
{
    __shared__ int wsum[16];
    __shared__ int carry;
    const int tid = threadIdx.x, wave = tid >> 6, lane = tid & 63;
    if (tid == 0) carry = 0;
    __syncthreads();
    for (int base = 0; base < N_NODES; base += 1024) {
        const int i = base + tid;
        const int v = (i < N_NODES) ? deg[i] : 0;
        int s = v;
#pragma unroll
        for (int d = 1; d < 64; d <<= 1) {
            const int t = __shfl_up(s, d);
            if (lane >= d) s += t;
        }
        if (lane == 63) wsum[wave] = s;
        __syncthreads();
        if (wave == 0) {
            int t = (lane < 16) ? wsum[lane] : 0;
#pragma unroll
            for (int d = 1; d < 16; d <<= 1) {
                const int u = __shfl_up(t, d);
                if (lane >= d) t += u;
            }
            if (lane < 16) wsum[lane] = t;
        }
        __syncthreads();
        const int wbase = (wave == 0) ? 0 : wsum[wave - 1];
        if (i < N_NODES) {
            const int o = carry + wbase + s - v;
            off[i] = o;
            cur[i] = o;
        }
        const int tot = wsum[15];
        __syncthreads();
        if (tid == 0) carry += tot;
        __syncthreads();
    }
    if (tid == 0) off[N_NODES] = carry;

    // graph boundaries (batch is sorted)
    if (tid <= N_GRAPHS) {
        if (tid == N_GRAPHS) { start[N_GRAPHS] = N_NODES; }
        else {
            int lo = 0, hi = N_NODES;
            while (lo < hi) { const int mid = (lo + hi) >> 1; if (batch[mid] < tid) lo = mid + 1; else hi = mid; }
            start[tid] = lo;
        }
    }
}

// light scatter: dst-sorted (src, eid) pairs only — 2.5 MB
__global__ __launch_bounds__(256) void scatter_kernel(
    const int* __restrict__ src, const int* __restrict__ dst,
    int* __restrict__ cursor, int2* __restrict__ sidx)
{
    const int e = blockIdx.x * 256 + threadIdx.x;
    if (e < N_EDGES) {
        const int p = atomicAdd(cursor + dst[e], 1);
        sidx[p] = make_int2(src[e], e);
    }
}

// ---------------------------------------------------------------------------
// agg3 v3 — rocprof evidence from v2 (VGPR=36 with >=52 live values needed,
// VALUBusy 44%, ~2800 wall-cycles/edge) says the per-edge state is in
// SCRATCH: `(&vec.x)[j]` pointer-indexed member access on HIP struct vector
// types forces an alloca that SROA fails to promote. v3 removes every such
// pattern: all per-edge data is clang ext_vector (extractelement indexing),
// bf16 unpack is pure bit-ops, output is packed manually. Schedule (vector
// loads via divergence-injection, sidx 2 ahead, data 1 ahead) kept from v2.
// out[v] = bf16( x[v] + sum_e relu(x[src] + ea@We.T + be) )
// ---------------------------------------------------------------------------
template<int IN>
__global__ __launch_bounds__(256, 4) void agg3(
    const unsigned short* __restrict__ xb,   // [M_PAD, IN] bf16
    const unsigned short* __restrict__ eah,  // [E,16] f16 (original edge order)
    const int2* __restrict__ sidx,           // (src, eid) sorted by dst
    const int* __restrict__ off,             // [N+1]
    const unsigned short* __restrict__ Weh,  // [IN,16] f16
    const float* __restrict__ be,
    unsigned short* __restrict__ out)        // [M_PAD, IN] bf16
{
    constexpr int CPL = IN / 64;             // 2 (layer1) or 4
    constexpr int XW  = CPL / 2;             // x-row dwords per lane: 1 or 2
    const int lane = threadIdx.x & 63;
    const int node = blockIdx.x * 4 + (threadIdx.x >> 6);
    if (node >= N_NODES) return;
    const int c0 = lane * CPL;
    const int zd = __builtin_amdgcn_mbcnt_lo(0u, 0u);   // divergent zero: defeats SMEM scalarization
    const u32x2* sv = (const u32x2*)sidx;

    // x-row loader: always returns u32x2; CPL==2 uses only element 0
    auto loadx = [&](int s) -> u32x2 {
        if constexpr (XW == 2) {
            return *(const u32x2*)(xb + (size_t)s * IN + c0);
        } else {
            u32x2 r;
            r[0] = *(const unsigned int*)(xb + (size_t)s * IN + c0);
            r[1] = 0u;
            return r;
        }
    };

    // weights: CPL rows x 16 f16 = CPL x (u32x4 lo, u32x4 hi) — resident
    u32x4 wlo[CPL], whi[CPL];
    float bias[CPL], acc[CPL];
#pragma unroll
    for (int j = 0; j < CPL; ++j) {
        const u32x4* wr = (const u32x4*)(Weh + (size_t)(c0 + j) * 16);
        wlo[j] = wr[0];
        whi[j] = wr[1];
        bias[j] = be[c0 + j];
        acc[j]  = 0.0f;
    }

    const int p0 = __builtin_amdgcn_readfirstlane(off[node]);
    const int p1 = __builtin_amdgcn_readfirstlane(off[node + 1]);

    u32x4 eLo, eHi;
    u32x2 xv;
    int sN = 0, eN = 0;                      // ids for edge p+1 (VGPRs)
    if (p0 < p1) {
        const u32x2 se0 = sv[p0 + zd];
        const u32x4* er = (const u32x4*)(eah + (size_t)se0[1] * 16);
        eLo = er[0]; eHi = er[1];
        xv = loadx((int)se0[0]);
        if (p0 + 1 < p1) {
            const u32x2 se1 = sv[p0 + 1 + zd];
            sN = (int)se1[0]; eN = (int)se1[1];
        }
    }

    for (int p = p0; p < p1; ++p) {
        // issue sidx[p+2] — consumed next iteration (address dep broken)
        int sF = 0, eF = 0;
        if (p + 2 < p1) {
            const u32x2 se = sv[p + 2 + zd];
            sF = (int)se[0]; eF = (int)se[1];
        }
        // issue data loads for edge p+1 (addresses already resolved)
        u32x4 eLoN, eHiN;
        u32x2 xvN;
        if (p + 1 < p1) {
            const u32x4* er = (const u32x4*)(eah + (size_t)eN * 16);
            eLoN = er[0]; eHiN = er[1];
            xvN = loadx(sN);
        }
        // compute on current edge (f16 dot2, fp32 accumulate)
        float m[CPL];
#pragma unroll
        for (int j = 0; j < CPL; ++j) m[j] = bias[j];
#pragma unroll
        for (int k = 0; k < 4; ++k) {
            const h2 ep = __builtin_bit_cast(h2, eLo[k]);
#pragma unroll
            for (int j = 0; j < CPL; ++j)
                m[j] = DOT2(ep, __builtin_bit_cast(h2, wlo[j][k]), m[j]);
        }
#pragma unroll
        for (int k = 0; k < 4; ++k) {
            const h2 ep = __builtin_bit_cast(h2, eHi[k]);
#pragma unroll
            for (int j = 0; j < CPL; ++j)
                m[j] = DOT2(ep, __builtin_bit_cast(h2, whi[j][k]), m[j]);
        }
        // add x_src (bf16 unpack: even col = word<<16, odd col = word&0xFFFF0000)
#pragma unroll
        for (int j = 0; j < CPL; ++j) {
            const unsigned int word = xv[j >> 1];
            const float xf = __builtin_bit_cast(float,
                (j & 1) ? (word & 0xFFFF0000u) : (word << 16));
            acc[j] += fmaxf(m[j] + xf, 0.0f);
        }
        // rotate pipeline state
        if (p + 1 < p1) {
            eLo = eLoN; eHi = eHiN; xv = xvN; sN = sF; eN = eF;
        }
    }

    // out[node] = bf16(x[node] + acc), packed manually (no struct members)
    if constexpr (XW == 2) {
        const u32x2 xs = *(const u32x2*)(xb + (size_t)node * IN + c0);
        const float x0 = __builtin_bit_cast(float, xs[0] << 16);
        const float x1 = __builtin_bit_cast(float, xs[0] & 0xFFFF0000u);
        const float x2 = __builtin_bit_cast(float, xs[1] << 16);
        const float x3 = __builtin_bit_cast(float, xs[1] & 0xFFFF0000u);
        u32x2 o;
        o[0] = (unsigned)f2bf(x0 + acc[0]) | ((unsigned)f2bf(x1 + acc[1]) << 16);
        o[1] = (unsigned)f2bf(x2 + acc[2]) | ((unsigned)f2bf(x3 + acc[3]) << 16);
        *(u32x2*)(out + (size_t)node * IN + c0) = o;
    } else {
        const unsigned int xs = *(const unsigned int*)(xb + (size_t)node * IN + c0);
        const float x0 = __builtin_bit_cast(float, xs << 16);
        const float x1 = __builtin_bit_cast(float, xs & 0xFFFF0000u);
        const unsigned int o =
            (unsigned)f2bf(x0 + acc[0]) | ((unsigned)f2bf(x1 + acc[1]) << 16);
        *(unsigned int*)(out + (size_t)node * IN + c0) = o;
    }
}

// ---------------------------------------------------------------------------
// B-in-register streaming GEMM v2 (best measured config, R9):
// grid (313,2), 4 waves/block, wave owns 32 cols with K resident in regs;
// 4 chunks of 16 rows with 2-deep prefetch. No LDS, no barriers.
// EPI 0: BN(eval)+relu -> bf16 (all rows)   EPI 1: bias+relu (rows < N)
// ---------------------------------------------------------------------------
template<int K, int EPI>
__global__ __launch_bounds__(256) void gemm_breg2(
    const unsigned short* __restrict__ A,    // [M_PAD, K]
    const unsigned short* __restrict__ W,    // [256, K]
    const float* __restrict__ bias,
    const float* __restrict__ gsc, const float* __restrict__ bsh,
    unsigned short* __restrict__ out)        // [M_PAD, 256]
{
    constexpr int KC = K / 32;               // 4 or 8 k-chunks
    const int w = threadIdx.x >> 6, lane = threadIdx.x & 63;
    const int lm = lane & 15, lq = lane >> 4;
    const int n0 = (blockIdx.y * 4 + w) * 32;
    const int m0 = blockIdx.x * 64;

    // B resident in registers
    bf16x8 B0[KC], B1[KC];
    {
        const unsigned short* Wp0 = W + (size_t)(n0 + lm) * K + lq * 8;
        const unsigned short* Wp1 = W + (size_t)(n0 + 16 + lm) * K + lq * 8;
#pragma unroll
        for (int c = 0; c < KC; ++c) {
            B0[c] = *(const bf16x8*)(Wp0 + c * 32);
            B1[c] = *(const bf16x8*)(Wp1 + c * 32);
        }
    }

    const float inv = rsqrtf(1.0f + 1e-5f);
    const float bc0 = bias[n0 + lm],      bc1 = bias[n0 + 16 + lm];
    const float gc0 = (EPI == 0) ? gsc[n0 + lm]      : 0.0f;
    const float gc1 = (EPI == 0) ? gsc[n0 + 16 + lm] : 0.0f;
    const float sc0 = (EPI == 0) ? bsh[n0 + lm]      : 0.0f;
    const float sc1 = (EPI == 0) ? bsh[n0 + 16 + lm] : 0.0f;

    bf16x8 aC[KC], aN[KC];
    {
        const unsigned short* Ap = A + (size_t)(m0 + lm) * K + lq * 8;
#pragma unroll
        for (int c = 0; c < KC; ++c) aC[c] = *(const bf16x8*)(Ap + c * 32);
    }

#pragma unroll
    for (int ch = 0; ch < 4; ++ch) {
        if (ch < 3) {
            const unsigned short* Ap = A + (size_t)(m0 + (ch + 1) * 16 + lm) * K + lq * 8;
#pragma unroll
            for (int c = 0; c < KC; ++c) aN[c] = *(const bf16x8*)(Ap + c * 32);
        }

        f32x4 acc0 = (f32x4){0.f, 0.f, 0.f, 0.f};
        f32x4 acc1 = (f32x4){0.f, 0.f, 0.f, 0.f};
#pragma unroll
        for (int c = 0; c < KC; ++c) {
            acc0 = __builtin_amdgcn_mfma_f32_16x16x32_bf16(aC[c], B0[c], acc0, 0, 0, 0);
            acc1 = __builtin_amdgcn_mfma_f32_16x16x32_bf16(aC[c], B1[c], acc1, 0, 0, 0);
        }

        const int mr = m0 + ch * 16;
#pragma unroll
        for (int r = 0; r < 4; ++r) {
            const int row = mr + lq * 4 + r;
            if (EPI == 1 && row >= N_NODES) continue;
            float v0 = acc0[r] + bc0;
            float v1 = acc1[r] + bc1;
            if (EPI == 0) {
                v0 = fmaxf(v0 * inv * gc0 + sc0, 0.0f);
                v1 = fmaxf(v1 * inv * gc1 + sc1, 0.0f);
            } else {
                v0 = fmaxf(v0, 0.0f);
                v1 = fmaxf(v1, 0.0f);
            }
            out[(size_t)row * H + n0 + lm]      = f2bf(v0);
            out[(size_t)row * H + n0 + 16 + lm] = f2bf(v1);
        }

#pragma unroll
        for (int c = 0; c < KC; ++c) aC[c] = aN[c];
    }
}

// ---------------------------------------------------------------------------
// Parallel mean-pool: grid (192, RSPLIT). Block (g, layer, chunk) reduces
// ~rows/RSPLIT rows and atomicAdds one partial per column into pool.
// ---------------------------------------------------------------------------
#define RSPLIT 6
__global__ __launch_bounds__(256) void pool2(
    const unsigned short* __restrict__ h1, const unsigned short* __restrict__ h2,
    const unsigned short* __restrict__ h3, const int* __restrict__ start,
    float* __restrict__ pool)
{
    const int g = blockIdx.x & 63, layer = blockIdx.x >> 6;
    const unsigned short* h = (layer == 0) ? h1 : (layer == 1) ? h2 : h3;
    const int r0 = start[g], r1 = start[g + 1];
    const int nr = r1 - r0;
    if (nr <= 0) return;
    const int chunk = (nr + RSPLIT - 1) / RSPLIT;
    const int rs = r0 + blockIdx.y * chunk;
    const int re = (rs + chunk < r1) ? rs + chunk : r1;
    if (rs >= re) return;

    const int c = threadIdx.x;
    float s0 = 0.f, s1 = 0.f, s2 = 0.f, s3 = 0.f;
    int r = rs;
    for (; r + 4 <= re; r += 4) {
        s0 += bf2f(h[(size_t)(r + 0) * H + c]);
        s1 += bf2f(h[(size_t)(r + 1) * H + c]);
        s2 += bf2f(h[(size_t)(r + 2) * H + c]);
        s3 += bf2f(h[(size_t)(r + 3) * H + c]);
    }
    for (; r < re; ++r) s0 += bf2f(h[(size_t)r * H + c]);
    atomicAdd(&pool[(size_t)g * POOL_W + layer * 256 + c], s0 + s1 + s2 + s3);
}

// ---------------------------------------------------------------------------
// FC head: one block per graph; pool is pre-summed (divide by count here).
// ---------------------------------------------------------------------------
__global__ __launch_bounds__(256) void final_kernel(
    const float* __restrict__ pool, const int* __restrict__ start,
    const float* __restrict__ L1w, const float* __restrict__ L1b,
    const float* __restrict__ L2w, const float* __restrict__ L2b,
    float* __restrict__ out)
{
    const int g = blockIdx.x;
    __shared__ float p[POOL_W];
    __shared__ float f1[POOL_W];
    __shared__ float red[4];

    const float rc = 1.0f / fmaxf((float)(start[g + 1] - start[g]), 1.0f);
    for (int i = threadIdx.x; i < POOL_W; i += 256)
        p[i] = pool[(size_t)g * POOL_W + i] * rc;
    __syncthreads();

    for (int r = 0; r < 3; ++r) {
        const int o = r * 256 + threadIdx.x;
        float acc = L1b[o];
        const float4* wrow = (const float4*)(L1w + (size_t)o * POOL_W);
        for (int k4 = 0; k4 < POOL_W / 4; ++k4) {
            const float4 w4 = wrow[k4];
            acc += w4.x * p[k4 * 4 + 0] + w4.y * p[k4 * 4 + 1]
                 + w4.z * p[k4 * 4 + 2] + w4.w * p[k4 * 4 + 3];
        }
        f1[o] = fmaxf(acc, 0.0f);
    }
    __syncthreads();

    float part = 0.0f;
    for (int i = threadIdx.x; i < POOL_W; i += 256) part += f1[i] * L2w[i];
#pragma unroll
    for (int off = 32; off > 0; off >>= 1) part += __shfl_down(part, off);
    if ((threadIdx.x & 63) == 0) red[threadIdx.x >> 6] = part;
    __syncthreads();
    if (threadIdx.x == 0) {
        const float s = red[0] + red[1] + red[2] + red[3] + L2b[0];
        out[g] = 1.0f / (1.0f + expf(-s));
    }
}

// ---------------------------------------------------------------------------
extern "C" void kernel_launch(void* const* d_in, const int* in_sizes, int n_in,
                              void* d_out, int out_size, void* d_ws, size_t ws_size,
                              hipStream_t stream)
{
    const float* x     = (const float*)d_in[0];
    const float* ea    = (const float*)d_in[1];
    const int*   src   = (const int*)d_in[2];
    const int*   dst   = (const int*)d_in[3];
    const int*   batch = (const int*)d_in[4];

    const float* We[3]; const float* be[3]; const float* Wa[3]; const float* ba[3];
    const float* gg[3]; const float* bt[3]; const float* Wb[3]; const float* bb[3];
    for (int l = 0; l < 3; ++l) {
        const int o = 5 + 8 * l;
        We[l] = (const float*)d_in[o + 0]; be[l] = (const float*)d_in[o + 1];
        Wa[l] = (const float*)d_in[o + 2]; ba[l] = (const float*)d_in[o + 3];
        gg[l] = (const float*)d_in[o + 4]; bt[l] = (const float*)d_in[o + 5];
        Wb[l] = (const float*)d_in[o + 6]; bb[l] = (const float*)d_in[o + 7];
    }
    const float* L1w = (const float*)d_in[29];
    const float* L1b = (const float*)d_in[30];
    const float* L2w = (const float*)d_in[31];
    const float* L2b = (const float*)d_in[32];

    // ---- workspace layout ----
    float* pool   = (float*)d_ws;                              // 64*768
    int*   deg    = (int*)(pool + (size_t)N_GRAPHS * POOL_W);  // N
    int*   off    = deg + N_NODES;                             // N+1
    int*   cursor = off + N_NODES + 1;                         // N
    int*   start  = cursor + N_NODES;                          // 72
    int2*  sidx   = (int2*)((((uintptr_t)(start + 72)) + 15) & ~(uintptr_t)15);  // E
    unsigned short* xb = (unsigned short*)((((uintptr_t)(sidx + N_EDGES)) + 15) & ~(uintptr_t)15);
    unsigned short* u  = xb + (size_t)M_PAD * DIN;             // [M_PAD,256] (layer1 uses 128)
    unsigned short* tT = u  + (size_t)M_PAD * H;               // [M_PAD,256] intermediate
    unsigned short* h1 = tT + (size_t)M_PAD * H;
    unsigned short* h2 = h1 + (size_t)M_PAD * H;
    unsigned short* h3 = h2 + (size_t)M_PAD * H;
    unsigned short* wbf[6];
    wbf[0] = h3 + (size_t)M_PAD * H;                           // Wa1 [256,128]
    wbf[1] = wbf[0] + H * DIN;
    for (int i = 2; i < 6; ++i) wbf[i] = wbf[i - 1] + H * H;
    unsigned short* eah = wbf[5] + H * H;                      // [E,16] f16
    unsigned short* weh[3];
    weh[0] = eah + (size_t)N_EDGES * 16;                       // We1 [128,16] f16
    weh[1] = weh[0] + DIN * 16;                                // We2 [256,16] f16
    weh[2] = weh[1] + H * 16;                                  // We3 [256,16] f16

    // batched converts + deg/pool zeroing in one launch (13 jobs)
    CvtJobs jobs;
    jobs.j[0]  = { x,       xb,                    N_NODES * DIN / 4,       0 };
    jobs.j[1]  = { Wa[0],   wbf[0],                H * DIN / 4,             0 };
    jobs.j[2]  = { Wb[0],   wbf[1],                H * H / 4,               0 };
    jobs.j[3]  = { Wa[1],   wbf[2],                H * H / 4,               0 };
    jobs.j[4]  = { Wb[1],   wbf[3],                H * H / 4,               0 };
    jobs.j[5]  = { Wa[2],   wbf[4],                H * H / 4,               0 };
    jobs.j[6]  = { Wb[2],   wbf[5],                H * H / 4,               0 };
    jobs.j[7]  = { nullptr, (unsigned short*)deg,  N_NODES * 4 / 8,         2 };  // zero N ints
    jobs.j[8]  = { nullptr, (unsigned short*)pool, N_GRAPHS * POOL_W * 4 / 8, 2 };// zero pool
    jobs.j[9]  = { ea,      eah,                   N_EDGES * 16 / 4,        1 };  // ea -> f16
    jobs.j[10] = { We[0],   weh[0],                DIN * 16 / 4,            1 };
    jobs.j[11] = { We[1],   weh[1],                H * 16 / 4,              1 };
    jobs.j[12] = { We[2],   weh[2],                H * 16 / 4,              1 };
    cvt_all<<<dim3(320, 13), 256, 0, stream>>>(jobs);

    // CSR + graph boundaries
    hist_kernel<<<(N_EDGES + 255) / 256, 256, 0, stream>>>(dst, deg);
    scan_kernel<<<1, 1024, 0, stream>>>(deg, off, cursor, batch, start);
    scatter_kernel<<<(N_EDGES + 255) / 256, 256, 0, stream>>>(src, dst, cursor, sidx);

    const int  agrid = (N_NODES + 3) / 4;       // agg3: 1 node/wave
    const dim3 ggrid(M_PAD / 64, 2);            // (313, 2)

    // ---- layer 1 (in=128) ----
    agg3<DIN><<<agrid, 256, 0, stream>>>(xb, eah, sidx, off, weh[0], be[0], u);
    gemm_breg2<DIN, 0><<<ggrid, 256, 0, stream>>>(u, wbf[0], ba[0], gg[0], bt[0], tT);
    gemm_breg2<H,   1><<<ggrid, 256, 0, stream>>>(tT, wbf[1], bb[0], nullptr, nullptr, h1);
    // ---- layer 2 ----
    agg3<H><<<agrid, 256, 0, stream>>>(h1, eah, sidx, off, weh[1], be[1], u);
    gemm_breg2<H, 0><<<ggrid, 256, 0, stream>>>(u, wbf[2], ba[1], gg[1], bt[1], tT);
    gemm_breg2<H, 1><<<ggrid, 256, 0, stream>>>(tT, wbf[3], bb[1], nullptr, nullptr, h2);
    // ---- layer 3 ----
    agg3<H><<<agrid, 256, 0, stream>>>(h2, eah, sidx, off, weh[2], be[2], u);
    gemm_breg2<H, 0><<<ggrid, 256, 0, stream>>>(u, wbf[4], ba[2], gg[2], bt[2], tT);
    gemm_breg2<H, 1><<<ggrid, 256, 0, stream>>>(tT, wbf[5], bb[2], nullptr, nullptr, h3);

    // parallel mean-pool + head
    pool2<<<dim3(3 * N_GRAPHS, RSPLIT), 256, 0, stream>>>(h1, h2, h3, start, pool);
    final_kernel<<<N_GRAPHS, 256, 0, stream>>>(pool, start, L1w, L1b, L2w, L2b, (float*)d_out);
}

// Round 3
// 563.768 us; speedup vs baseline: 1.0678x; 1.0007x over previous
//
#include <hip/hip_runtime.h>
#include <math.h>
#include <stdint.h>

#define N_NODES 20000
#define M_PAD 20032            // 313 * 64
#define N_EDGES 320000
#define N_GRAPHS 64
#define DIN 128
#define H 256
#define POOL_W 768

typedef __attribute__((ext_vector_type(8))) short bf16x8;   // 8 bf16 = 4 VGPRs
typedef __attribute__((ext_vector_type(4))) float f32x4;
typedef __attribute__((ext_vector_type(4))) unsigned int u32x4;
typedef __attribute__((ext_vector_type(2))) unsigned int u32x2;
typedef _Float16 h2 __attribute__((ext_vector_type(2)));    // packed f16 pair (1 VGPR)

__device__ __forceinline__ unsigned short f2bf(float f) {
    unsigned u = __builtin_bit_cast(unsigned, f);
    u += 0x7FFFu + ((u >> 16) & 1u);          // round-to-nearest-even
    return (unsigned short)(u >> 16);
}
__device__ __forceinline__ float bf2f(unsigned short u) {
    return __builtin_bit_cast(float, (unsigned)u << 16);
}
__device__ __forceinline__ unsigned short f2h(float f) {
    const _Float16 h = (_Float16)f;
    return __builtin_bit_cast(unsigned short, h);
}

#if __has_builtin(__builtin_amdgcn_fdot2)
#define DOT2(a, b, c) __builtin_amdgcn_fdot2((a), (b), (c), false)
#else
__device__ __forceinline__ float dot2_fallback(h2 a, h2 b, float c) {
    return fmaf((float)a.x, (float)b.x, fmaf((float)a.y, (float)b.y, c));
}
#define DOT2(a, b, c) dot2_fallback((a), (b), (c))
#endif

// ---------------------------------------------------------------------------
// Batched converts + zero jobs: 13 jobs, one launch.
// mode 0: fp32 -> bf16   mode 1: fp32 -> f16   mode 2: zero fill
// ---------------------------------------------------------------------------
struct CvtJob  { const float* s; unsigned short* d; int n4; int mode; };
struct CvtJobs { CvtJob j[13]; };

__global__ __launch_bounds__(256) void cvt_all(CvtJobs jobs)
{
    const CvtJob J = jobs.j[blockIdx.y];
    if (J.mode == 2) {
        const ushort4 z = {0, 0, 0, 0};
        for (int i = blockIdx.x * 256 + threadIdx.x; i < J.n4; i += gridDim.x * 256)
            ((ushort4*)J.d)[i] = z;
        return;
    }
    if (J.mode == 1) {
        for (int i = blockIdx.x * 256 + threadIdx.x; i < J.n4; i += gridDim.x * 256) {
            const float4 v = ((const float4*)J.s)[i];
            ushort4 r;
            r.x = f2h(v.x); r.y = f2h(v.y); r.z = f2h(v.z); r.w = f2h(v.w);
            ((ushort4*)J.d)[i] = r;
        }
        return;
    }
    for (int i = blockIdx.x * 256 + threadIdx.x; i < J.n4; i += gridDim.x * 256) {
        const float4 v = ((const float4*)J.s)[i];
        ushort4 r;
        r.x = f2bf(v.x); r.y = f2bf(v.y); r.z = f2bf(v.z); r.w = f2bf(v.w);
        ((ushort4*)J.d)[i] = r;
    }
}

// ---------------------------------------------------------------------------
// CSR build
// ---------------------------------------------------------------------------
__global__ __launch_bounds__(256) void hist_kernel(const int* __restrict__ dst,
                                                   int* __restrict__ deg)
{
    const int i = blockIdx.x * 256 + threadIdx.x;
    if (i < N_EDGES) atomicAdd(deg + dst[i], 1);
}

// shfl scan; writes off and cursor; tail threads also compute graph starts
__global__ __launch_bounds__(1024) void scan_kernel(const int* __restrict__ deg,
                                                    int* __restrict__ off,
                                                    int* __restrict__ cur,
                                                    const int* __restrict__ batch,
                                                    int* __restrict__ start)
{
    __shared__ int wsum[16];
    __shared__ int carry;
    const int tid = threadIdx.x, wave = tid >> 6, lane = tid & 63;
    if (tid == 0) carry = 0;
    __syncthreads();
    for (int base = 0; base < N_NODES; base += 1024) {
        const int i = base + tid;
        const int v = (i < N_NODES) ? deg[i] : 0;
        int s = v;
#pragma unroll
        for (int d = 1; d < 64; d <<= 1) {
            const int t = __shfl_up(s, d);
            if (lane >= d) s += t;
        }
        if (lane == 63) wsum[wave] = s;
        __syncthreads();
        if (wave == 0) {
            int t = (lane < 16) ? wsum[lane] : 0;
#pragma unroll
            for (int d = 1; d < 16; d <<= 1) {
                const int u = __shfl_up(t, d);
                if (lane >= d) t += u;
            }
            if (lane < 16) wsum[lane] = t;
        }
        __syncthreads();
        const int wbase = (wave == 0) ? 0 : wsum[wave - 1];
        if (i < N_NODES) {
            const int o = carry + wbase + s - v;
            off[i] = o;
            cur[i] = o;
        }
        const int tot = wsum[15];
        __syncthreads();
        if (tid == 0) carry += tot;
        __syncthreads();
    }
    if (tid == 0) off[N_NODES] = carry;

    // graph boundaries (batch is sorted)
    if (tid <= N_GRAPHS) {
        if (tid == N_GRAPHS) { start[N_GRAPHS] = N_NODES; }
        else {
            int lo = 0, hi = N_NODES;
            while (lo < hi) { const int mid = (lo + hi) >> 1; if (batch[mid] < tid) lo = mid + 1; else hi = mid; }
            start[tid] = lo;
        }
    }
}

// light scatter: dst-sorted (src, eid) pairs only — 2.5 MB
__global__ __launch_bounds__(256) void scatter_kernel(
    const int* __restrict__ src, const int* __restrict__ dst,
    int* __restrict__ cursor, int2* __restrict__ sidx)
{
    const int e = blockIdx.x * 256 + threadIdx.x;
    if (e < N_EDGES) {
        const int p = atomicAdd(cursor + dst[e], 1);
        sidx[p] = make_int2(src[e], e);
    }
}

// ---------------------------------------------------------------------------
// agg3 v4 — v3 post-mortem: VGPR=28 proves the We weights (32 dwords for
// CPL=4) were NOT register-resident: without v2's asm pin the compiler sank
// the weight loads into the edge loop (8 loads + lgkm wait per edge), and
// the 1-edge-deep pipeline left only ~4 loads in flight against a ~900cy
// HBM gather (VALUBusy 47% @ 63% occ ⇒ ~1 wave computing per SIMD).
// v4: (a) re-pin weights+bias in VGPRs via empty-asm on the clean
// ext_vector state; (b) unroll-by-2 IN-PLACE pipeline: compute edge i from
// buffer A, then overwrite A with loads for i+2 (ids prefetched one pair
// ahead, branch-free clamped indices) — ~8 loads in flight, no rotate movs,
// no per-iteration branches. Loaded data is NOT pinned (a pin would force
// a waitcnt at the load site and kill the prefetch).
// out[v] = bf16( x[v] + sum_e relu(x[src] + ea@We.T + be) )
// ---------------------------------------------------------------------------
template<int IN>
__global__ __launch_bounds__(256, 4) void agg3(
    const unsigned short* __restrict__ xb,   // [M_PAD, IN] bf16
    const unsigned short* __restrict__ eah,  // [E,16] f16 (original edge order)
    const int2* __restrict__ sidx,           // (src, eid) sorted by dst
    const int* __restrict__ off,             // [N+1]
    const unsigned short* __restrict__ Weh,  // [IN,16] f16
    const float* __restrict__ be,
    unsigned short* __restrict__ out)        // [M_PAD, IN] bf16
{
    constexpr int CPL = IN / 64;             // 2 (layer1) or 4
    constexpr int XW  = CPL / 2;             // x-row dwords per lane: 1 or 2
    const int lane = threadIdx.x & 63;
    const int node = blockIdx.x * 4 + (threadIdx.x >> 6);
    if (node >= N_NODES) return;
    const int c0 = lane * CPL;
    const int zd = __builtin_amdgcn_mbcnt_lo(0u, 0u);   // divergent zero: defeats SMEM scalarization
    const u32x2* sv = (const u32x2*)sidx;

    // weights: CPL rows x 16 f16 = CPL x (u32x4 lo, u32x4 hi) — pinned resident
    u32x4 wlo[CPL], whi[CPL];
    float bias[CPL], acc[CPL];
#pragma unroll
    for (int j = 0; j < CPL; ++j) {
        const u32x4* wr = (const u32x4*)(Weh + (size_t)(c0 + j) * 16);
        wlo[j] = wr[0];
        whi[j] = wr[1];
        bias[j] = be[c0 + j];
        acc[j]  = 0.0f;
    }
    // pin weights + bias in VGPRs: opaque def prevents the allocator from
    // sinking these loads into the edge loop (v3 regression: VGPR=28).
#pragma unroll
    for (int j = 0; j < CPL; ++j) {
#pragma unroll
        for (int k = 0; k < 4; ++k) {
            { float t = __builtin_bit_cast(float, wlo[j][k]); asm("" : "+v"(t)); wlo[j][k] = __builtin_bit_cast(unsigned int, t); }
            { float t = __builtin_bit_cast(float, whi[j][k]); asm("" : "+v"(t)); whi[j][k] = __builtin_bit_cast(unsigned int, t); }
        }
        asm("" : "+v"(bias[j]));
    }

    const int p0 = __builtin_amdgcn_readfirstlane(off[node]);
    const int p1 = __builtin_amdgcn_readfirstlane(off[node + 1]);
    const int n  = p1 - p0;

    // x-row loader: always returns u32x2; CPL==2 uses only element 0
    auto ldx = [&](u32x2 id) -> u32x2 {
        const int s = (int)id[0];
        if constexpr (XW == 2) {
            return *(const u32x2*)(xb + (size_t)s * IN + c0);
        } else {
            u32x2 r;
            r[0] = *(const unsigned int*)(xb + (size_t)s * IN + c0);
            r[1] = 0u;
            return r;
        }
    };
    auto ldeaL = [&](u32x2 id) -> u32x4 {
        return ((const u32x4*)(eah + (size_t)id[1] * 16))[0];
    };
    auto ldeaH = [&](u32x2 id) -> u32x4 {
        return ((const u32x4*)(eah + (size_t)id[1] * 16))[1];
    };
    // clamped id fetch (branch-free; valid for any i when n > 0)
    auto ldid = [&](int i) -> u32x2 {
        const int q = (i < n) ? i : (n - 1);
        return sv[p0 + q + zd];
    };
    auto edge_compute = [&](u32x4 eL, u32x4 eH, u32x2 xw) {
        float m[CPL];
#pragma unroll
        for (int j = 0; j < CPL; ++j) m[j] = bias[j];
#pragma unroll
        for (int k = 0; k < 4; ++k) {
            const h2 ep = __builtin_bit_cast(h2, eL[k]);
#pragma unroll
            for (int j = 0; j < CPL; ++j)
                m[j] = DOT2(ep, __builtin_bit_cast(h2, wlo[j][k]), m[j]);
        }
#pragma unroll
        for (int k = 0; k < 4; ++k) {
            const h2 ep = __builtin_bit_cast(h2, eH[k]);
#pragma unroll
            for (int j = 0; j < CPL; ++j)
                m[j] = DOT2(ep, __builtin_bit_cast(h2, whi[j][k]), m[j]);
        }
        // add x_src (bf16 unpack: even col = word<<16, odd col = word&0xFFFF0000)
#pragma unroll
        for (int j = 0; j < CPL; ++j) {
            const unsigned int word = xw[j >> 1];
            const float xf = __builtin_bit_cast(float,
                (j & 1) ? (word & 0xFFFF0000u) : (word << 16));
            acc[j] += fmaxf(m[j] + xf, 0.0f);
        }
    };

    if (n > 0) {
        u32x2 idA = ldid(0), idB = ldid(1);
        u32x2 idC = ldid(2), idD = ldid(3);
        u32x4 eLA = ldeaL(idA), eHA = ldeaH(idA); u32x2 xA = ldx(idA);
        u32x4 eLB = ldeaL(idB), eHB = ldeaH(idB); u32x2 xB = ldx(idB);

        int i = 0;
        for (; i + 2 <= n; i += 2) {
            edge_compute(eLA, eHA, xA);
            eLA = ldeaL(idC); eHA = ldeaH(idC); xA = ldx(idC);   // data for i+2
            idC = ldid(i + 4);
            edge_compute(eLB, eHB, xB);
            eLB = ldeaL(idD); eHB = ldeaH(idD); xB = ldx(idD);   // data for i+3
            idD = ldid(i + 5);
        }
        if (i < n) edge_compute(eLA, eHA, xA);                   // odd tail
    }

    // out[node] = bf16(x[node] + acc), packed manually
    if constexpr (XW == 2) {
        const u32x2 xs = *(const u32x2*)(xb + (size_t)node * IN + c0);
        const float x0 = __builtin_bit_cast(float, xs[0] << 16);
        const float x1 = __builtin_bit_cast(float, xs[0] & 0xFFFF0000u);
        const float x2 = __builtin_bit_cast(float, xs[1] << 16);
        const float x3 = __builtin_bit_cast(float, xs[1] & 0xFFFF0000u);
        u32x2 o;
        o[0] = (unsigned)f2bf(x0 + acc[0]) | ((unsigned)f2bf(x1 + acc[1]) << 16);
        o[1] = (unsigned)f2bf(x2 + acc[2]) | ((unsigned)f2bf(x3 + acc[3]) << 16);
        *(u32x2*)(out + (size_t)node * IN + c0) = o;
    } else {
        const unsigned int xs = *(const unsigned int*)(xb + (size_t)node * IN + c0);
        const float x0 = __builtin_bit_cast(float, xs << 16);
        const float x1 = __builtin_bit_cast(float, xs & 0xFFFF0000u);
        const unsigned int o =
            (unsigned)f2bf(x0 + acc[0]) | ((unsigned)f2bf(x1 + acc[1]) << 16);
        *(unsigned int*)(out + (size_t)node * IN + c0) = o;
    }
}

// ---------------------------------------------------------------------------
// B-in-register streaming GEMM v2 (best measured config, R9):
// grid (313,2), 4 waves/block, wave owns 32 cols with K resident in regs;
// 4 chunks of 16 rows with 2-deep prefetch. No LDS, no barriers.
// EPI 0: BN(eval)+relu -> bf16 (all rows)   EPI 1: bias+relu (rows < N)
// ---------------------------------------------------------------------------
template<int K, int EPI>
__global__ __launch_bounds__(256) void gemm_breg2(
    const unsigned short* __restrict__ A,    // [M_PAD, K]
    const unsigned short* __restrict__ W,    // [256, K]
    const float* __restrict__ bias,
    const float* __restrict__ gsc, const float* __restrict__ bsh,
    unsigned short* __restrict__ out)        // [M_PAD, 256]
{
    constexpr int KC = K / 32;               // 4 or 8 k-chunks
    const int w = threadIdx.x >> 6, lane = threadIdx.x & 63;
    const int lm = lane & 15, lq = lane >> 4;
    const int n0 = (blockIdx.y * 4 + w) * 32;
    const int m0 = blockIdx.x * 64;

    // B resident in registers
    bf16x8 B0[KC], B1[KC];
    {
        const unsigned short* Wp0 = W + (size_t)(n0 + lm) * K + lq * 8;
        const unsigned short* Wp1 = W + (size_t)(n0 + 16 + lm) * K + lq * 8;
#pragma unroll
        for (int c = 0; c < KC; ++c) {
            B0[c] = *(const bf16x8*)(Wp0 + c * 32);
            B1[c] = *(const bf16x8*)(Wp1 + c * 32);
        }
    }

    const float inv = rsqrtf(1.0f + 1e-5f);
    const float bc0 = bias[n0 + lm],      bc1 = bias[n0 + 16 + lm];
    const float gc0 = (EPI == 0) ? gsc[n0 + lm]      : 0.0f;
    const float gc1 = (EPI == 0) ? gsc[n0 + 16 + lm] : 0.0f;
    const float sc0 = (EPI == 0) ? bsh[n0 + lm]      : 0.0f;
    const float sc1 = (EPI == 0) ? bsh[n0 + 16 + lm] : 0.0f;

    bf16x8 aC[KC], aN[KC];
    {
        const unsigned short* Ap = A + (size_t)(m0 + lm) * K + lq * 8;
#pragma unroll
        for (int c = 0; c < KC; ++c) aC[c] = *(const bf16x8*)(Ap + c * 32);
    }

#pragma unroll
    for (int ch = 0; ch < 4; ++ch) {
        if (ch < 3) {
            const unsigned short* Ap = A + (size_t)(m0 + (ch + 1) * 16 + lm) * K + lq * 8;
#pragma unroll
            for (int c = 0; c < KC; ++c) aN[c] = *(const bf16x8*)(Ap + c * 32);
        }

        f32x4 acc0 = (f32x4){0.f, 0.f, 0.f, 0.f};
        f32x4 acc1 = (f32x4){0.f, 0.f, 0.f, 0.f};
#pragma unroll
        for (int c = 0; c < KC; ++c) {
            acc0 = __builtin_amdgcn_mfma_f32_16x16x32_bf16(aC[c], B0[c], acc0, 0, 0, 0);
            acc1 = __builtin_amdgcn_mfma_f32_16x16x32_bf16(aC[c], B1[c], acc1, 0, 0, 0);
        }

        const int mr = m0 + ch * 16;
#pragma unroll
        for (int r = 0; r < 4; ++r) {
            const int row = mr + lq * 4 + r;
            if (EPI == 1 && row >= N_NODES) continue;
            float v0 = acc0[r] + bc0;
            float v1 = acc1[r] + bc1;
            if (EPI == 0) {
                v0 = fmaxf(v0 * inv * gc0 + sc0, 0.0f);
                v1 = fmaxf(v1 * inv * gc1 + sc1, 0.0f);
            } else {
                v0 = fmaxf(v0, 0.0f);
                v1 = fmaxf(v1, 0.0f);
            }
            out[(size_t)row * H + n0 + lm]      = f2bf(v0);
            out[(size_t)row * H + n0 + 16 + lm] = f2bf(v1);
        }

#pragma unroll
        for (int c = 0; c < KC; ++c) aC[c] = aN[c];
    }
}

// ---------------------------------------------------------------------------
// Parallel mean-pool: grid (192, RSPLIT). Block (g, layer, chunk) reduces
// ~rows/RSPLIT rows and atomicAdds one partial per column into pool.
// ---------------------------------------------------------------------------
#define RSPLIT 6
__global__ __launch_bounds__(256) void pool2(
    const unsigned short* __restrict__ h1, const unsigned short* __restrict__ h2,
    const unsigned short* __restrict__ h3, const int* __restrict__ start,
    float* __restrict__ pool)
{
    const int g = blockIdx.x & 63, layer = blockIdx.x >> 6;
    const unsigned short* h = (layer == 0) ? h1 : (layer == 1) ? h2 : h3;
    const int r0 = start[g], r1 = start[g + 1];
    const int nr = r1 - r0;
    if (nr <= 0) return;
    const int chunk = (nr + RSPLIT - 1) / RSPLIT;
    const int rs = r0 + blockIdx.y * chunk;
    const int re = (rs + chunk < r1) ? rs + chunk : r1;
    if (rs >= re) return;

    const int c = threadIdx.x;
    float s0 = 0.f, s1 = 0.f, s2 = 0.f, s3 = 0.f;
    int r = rs;
    for (; r + 4 <= re; r += 4) {
        s0 += bf2f(h[(size_t)(r + 0) * H + c]);
        s1 += bf2f(h[(size_t)(r + 1) * H + c]);
        s2 += bf2f(h[(size_t)(r + 2) * H + c]);
        s3 += bf2f(h[(size_t)(r + 3) * H + c]);
    }
    for (; r < re; ++r) s0 += bf2f(h[(size_t)r * H + c]);
    atomicAdd(&pool[(size_t)g * POOL_W + layer * 256 + c], s0 + s1 + s2 + s3);
}

// ---------------------------------------------------------------------------
// FC head: one block per graph; pool is pre-summed (divide by count here).
// ---------------------------------------------------------------------------
__global__ __launch_bounds__(256) void final_kernel(
    const float* __restrict__ pool, const int* __restrict__ start,
    const float* __restrict__ L1w, const float* __restrict__ L1b,
    const float* __restrict__ L2w, const float* __restrict__ L2b,
    float* __restrict__ out)
{
    const int g = blockIdx.x;
    __shared__ float p[POOL_W];
    __shared__ float f1[POOL_W];
    __shared__ float red[4];

    const float rc = 1.0f / fmaxf((float)(start[g + 1] - start[g]), 1.0f);
    for (int i = threadIdx.x; i < POOL_W; i += 256)
        p[i] = pool[(size_t)g * POOL_W + i] * rc;
    __syncthreads();

    for (int r = 0; r < 3; ++r) {
        const int o = r * 256 + threadIdx.x;
        float acc = L1b[o];
        const float4* wrow = (const float4*)(L1w + (size_t)o * POOL_W);
        for (int k4 = 0; k4 < POOL_W / 4; ++k4) {
            const float4 w4 = wrow[k4];
            acc += w4.x * p[k4 * 4 + 0] + w4.y * p[k4 * 4 + 1]
                 + w4.z * p[k4 * 4 + 2] + w4.w * p[k4 * 4 + 3];
        }
        f1[o] = fmaxf(acc, 0.0f);
    }
    __syncthreads();

    float part = 0.0f;
    for (int i = threadIdx.x; i < POOL_W; i += 256) part += f1[i] * L2w[i];
#pragma unroll
    for (int off = 32; off > 0; off >>= 1) part += __shfl_down(part, off);
    if ((threadIdx.x & 63) == 0) red[threadIdx.x >> 6] = part;
    __syncthreads();
    if (threadIdx.x == 0) {
        const float s = red[0] + red[1] + red[2] + red[3] + L2b[0];
        out[g] = 1.0f / (1.0f + expf(-s));
    }
}

// ---------------------------------------------------------------------------
extern "C" void kernel_launch(void* const* d_in, const int* in_sizes, int n_in,
                              void* d_out, int out_size, void* d_ws, size_t ws_size,
                              hipStream_t stream)
{
    const float* x     = (const float*)d_in[0];
    const float* ea    = (const float*)d_in[1];
    const int*   src   = (const int*)d_in[2];
    const int*   dst   = (const int*)d_in[3];
    const int*   batch = (const int*)d_in[4];

    const float* We[3]; const float* be[3]; const float* Wa[3]; const float* ba[3];
    const float* gg[3]; const float* bt[3]; const float* Wb[3]; const float* bb[3];
    for (int l = 0; l < 3; ++l) {
        const int o = 5 + 8 * l;
        We[l] = (const float*)d_in[o + 0]; be[l] = (const float*)d_in[o + 1];
        Wa[l] = (const float*)d_in[o + 2]; ba[l] = (const float*)d_in[o + 3];
        gg[l] = (const float*)d_in[o + 4]; bt[l] = (const float*)d_in[o + 5];
        Wb[l] = (const float*)d_in[o + 6]; bb[l] = (const float*)d_in[o + 7];
    }
    const float* L1w = (const float*)d_in[29];
    const float* L1b = (const float*)d_in[30];
    const float* L2w = (const float*)d_in[31];
    const float* L2b = (const float*)d_in[32];

    // ---- workspace layout ----
    float* pool   = (float*)d_ws;                              // 64*768
    int*   deg    = (int*)(pool + (size_t)N_GRAPHS * POOL_W);  // N
    int*   off    = deg + N_NODES;                             // N+1
    int*   cursor = off + N_NODES + 1;                         // N
    int*   start  = cursor + N_NODES;                          // 72
    int2*  sidx   = (int2*)((((uintptr_t)(start + 72)) + 15) & ~(uintptr_t)15);  // E
    unsigned short* xb = (unsigned short*)((((uintptr_t)(sidx + N_EDGES)) + 15) & ~(uintptr_t)15);
    unsigned short* u  = xb + (size_t)M_PAD * DIN;             // [M_PAD,256] (layer1 uses 128)
    unsigned short* tT = u  + (size_t)M_PAD * H;               // [M_PAD,256] intermediate
    unsigned short* h1 = tT + (size_t)M_PAD * H;
    unsigned short* h2 = h1 + (size_t)M_PAD * H;
    unsigned short* h3 = h2 + (size_t)M_PAD * H;
    unsigned short* wbf[6];
    wbf[0] = h3 + (size_t)M_PAD * H;                           // Wa1 [256,128]
    wbf[1] = wbf[0] + H * DIN;
    for (int i = 2; i < 6; ++i) wbf[i] = wbf[i - 1] + H * H;
    unsigned short* eah = wbf[5] + H * H;                      // [E,16] f16
    unsigned short* weh[3];
    weh[0] = eah + (size_t)N_EDGES * 16;                       // We1 [128,16] f16
    weh[1] = weh[0] + DIN * 16;                                // We2 [256,16] f16
    weh[2] = weh[1] + H * 16;                                  // We3 [256,16] f16

    // batched converts + deg/pool zeroing in one launch (13 jobs)
    CvtJobs jobs;
    jobs.j[0]  = { x,       xb,                    N_NODES * DIN / 4,       0 };
    jobs.j[1]  = { Wa[0],   wbf[0],                H * DIN / 4,             0 };
    jobs.j[2]  = { Wb[0],   wbf[1],                H * H / 4,               0 };
    jobs.j[3]  = { Wa[1],   wbf[2],                H * H / 4,               0 };
    jobs.j[4]  = { Wb[1],   wbf[3],                H * H / 4,               0 };
    jobs.j[5]  = { Wa[2],   wbf[4],                H * H / 4,               0 };
    jobs.j[6]  = { Wb[2],   wbf[5],                H * H / 4,               0 };
    jobs.j[7]  = { nullptr, (unsigned short*)deg,  N_NODES * 4 / 8,         2 };  // zero N ints
    jobs.j[8]  = { nullptr, (unsigned short*)pool, N_GRAPHS * POOL_W * 4 / 8, 2 };// zero pool
    jobs.j[9]  = { ea,      eah,                   N_EDGES * 16 / 4,        1 };  // ea -> f16
    jobs.j[10] = { We[0],   weh[0],                DIN * 16 / 4,            1 };
    jobs.j[11] = { We[1],   weh[1],                H * 16 / 4,              1 };
    jobs.j[12] = { We[2],   weh[2],                H * 16 / 4,              1 };
    cvt_all<<<dim3(320, 13), 256, 0, stream>>>(jobs);

    // CSR + graph boundaries
    hist_kernel<<<(N_EDGES + 255) / 256, 256, 0, stream>>>(dst, deg);
    scan_kernel<<<1, 1024, 0, stream>>>(deg, off, cursor, batch, start);
    scatter_kernel<<<(N_EDGES + 255) / 256, 256, 0, stream>>>(src, dst, cursor, sidx);

    const int  agrid = (N_NODES + 3) / 4;       // agg3: 1 node/wave
    const dim3 ggrid(M_PAD / 64, 2);            // (313, 2)

    // ---- layer 1 (in=128) ----
    agg3<DIN><<<agrid, 256, 0, stream>>>(xb, eah, sidx, off, weh[0], be[0], u);
    gemm_breg2<DIN, 0><<<ggrid, 256, 0, stream>>>(u, wbf[0], ba[0], gg[0], bt[0], tT);
    gemm_breg2<H,   1><<<ggrid, 256, 0, stream>>>(tT, wbf[1], bb[0], nullptr, nullptr, h1);
    // ---- layer 2 ----
    agg3<H><<<agrid, 256, 0, stream>>>(h1, eah, sidx, off, weh[1], be[1], u);
    gemm_breg2<H, 0><<<ggrid, 256, 0, stream>>>(u, wbf[2], ba[1], gg[1], bt[1], tT);
    gemm_breg2<H, 1><<<ggrid, 256, 0, stream>>>(tT, wbf[3], bb[1], nullptr, nullptr, h2);
    // ---- layer 3 ----
    agg3<H><<<agrid, 256, 0, stream>>>(h2, eah, sidx, off, weh[2], be[2], u);
    gemm_breg2<H, 0><<<ggrid, 256, 0, stream>>>(u, wbf[4], ba[2], gg[2], bt[2], tT);
    gemm_breg2<H, 1><<<ggrid, 256, 0, stream>>>(tT, wbf[5], bb[2], nullptr, nullptr, h3);

    // parallel mean-pool + head
    pool2<<<dim3(3 * N_GRAPHS, RSPLIT), 256, 0, stream>>>(h1, h2, h3, start, pool);
    final_kernel<<<N_GRAPHS, 256, 0, stream>>>(pool, start, L1w, L1b, L2w, L2b, (float*)d_out);
}

// Round 4
// 530.075 us; speedup vs baseline: 1.1357x; 1.0636x over previous
//
#include <hip/hip_runtime.h>
#include <math.h>
#include <stdint.h>

#define N_NODES 20000
#define M_PAD 20032            // 313 * 64
#define N_EDGES 320000
#define N_GRAPHS 64
#define DIN 128
#define H 256
#define POOL_W 768

typedef __attribute__((ext_vector_type(8))) short bf16x8;   // 8 bf16 = 4 VGPRs
typedef __attribute__((ext_vector_type(4))) float f32x4;
typedef __attribute__((ext_vector_type(4))) unsigned int u32x4;
typedef __attribute__((ext_vector_type(2))) unsigned int u32x2;
typedef _Float16 h2 __attribute__((ext_vector_type(2)));    // packed f16 pair (1 VGPR)

__device__ __forceinline__ unsigned short f2bf(float f) {
    unsigned u = __builtin_bit_cast(unsigned, f);
    u += 0x7FFFu + ((u >> 16) & 1u);          // round-to-nearest-even
    return (unsigned short)(u >> 16);
}
__device__ __forceinline__ float bf2f(unsigned short u) {
    return __builtin_bit_cast(float, (unsigned)u << 16);
}
__device__ __forceinline__ unsigned short f2h(float f) {
    const _Float16 h = (_Float16)f;
    return __builtin_bit_cast(unsigned short, h);
}

#if __has_builtin(__builtin_amdgcn_fdot2)
#define DOT2(a, b, c) __builtin_amdgcn_fdot2((a), (b), (c), false)
#else
__device__ __forceinline__ float dot2_fallback(h2 a, h2 b, float c) {
    return fmaf((float)a.x, (float)b.x, fmaf((float)a.y, (float)b.y, c));
}
#define DOT2(a, b, c) dot2_fallback((a), (b), (c))
#endif

// ---------------------------------------------------------------------------
// Batched converts + zero jobs: 13 jobs, one launch.
// mode 0: fp32 -> bf16   mode 1: fp32 -> f16   mode 2: zero fill
// ---------------------------------------------------------------------------
struct CvtJob  { const float* s; unsigned short* d; int n4; int mode; };
struct CvtJobs { CvtJob j[13]; };

__global__ __launch_bounds__(256) void cvt_all(CvtJobs jobs)
{
    const CvtJob J = jobs.j[blockIdx.y];
    if (J.mode == 2) {
        const ushort4 z = {0, 0, 0, 0};
        for (int i = blockIdx.x * 256 + threadIdx.x; i < J.n4; i += gridDim.x * 256)
            ((ushort4*)J.d)[i] = z;
        return;
    }
    if (J.mode == 1) {
        for (int i = blockIdx.x * 256 + threadIdx.x; i < J.n4; i += gridDim.x * 256) {
            const float4 v = ((const float4*)J.s)[i];
            ushort4 r;
            r.x = f2h(v.x); r.y = f2h(v.y); r.z = f2h(v.z); r.w = f2h(v.w);
            ((ushort4*)J.d)[i] = r;
        }
        return;
    }
    for (int i = blockIdx.x * 256 + threadIdx.x; i < J.n4; i += gridDim.x * 256) {
        const float4 v = ((const float4*)J.s)[i];
        ushort4 r;
        r.x = f2bf(v.x); r.y = f2bf(v.y); r.z = f2bf(v.z); r.w = f2bf(v.w);
        ((ushort4*)J.d)[i] = r;
    }
}

// ---------------------------------------------------------------------------
// CSR build
// ---------------------------------------------------------------------------
__global__ __launch_bounds__(256) void hist_kernel(const int* __restrict__ dst,
                                                   int* __restrict__ deg)
{
    const int i = blockIdx.x * 256 + threadIdx.x;
    if (i < N_EDGES) atomicAdd(deg + dst[i], 1);
}

// shfl scan; writes off and cursor; tail threads also compute graph starts
__global__ __launch_bounds__(1024) void scan_kernel(const int* __restrict__ deg,
                                                    int* __restrict__ off,
                                                    int* __restrict__ cur,
                                                    const int* __restrict__ batch,
                                                    int* __restrict__ start)
{
    __shared__ int wsum[16];
    __shared__ int carry;
    const int tid = threadIdx.x, wave = tid >> 6, lane = tid & 63;
    if (tid == 0) carry = 0;
    __syncthreads();
    for (int base = 0; base < N_NODES; base += 1024) {
        const int i = base + tid;
        const int v = (i < N_NODES) ? deg[i] : 0;
        int s = v;
#pragma unroll
        for (int d = 1; d < 64; d <<= 1) {
            const int t = __shfl_up(s, d);
            if (lane >= d) s += t;
        }
        if (lane == 63) wsum[wave] = s;
        __syncthreads();
        if (wave == 0) {
            int t = (lane < 16) ? wsum[lane] : 0;
#pragma unroll
            for (int d = 1; d < 16; d <<= 1) {
                const int u = __shfl_up(t, d);
                if (lane >= d) t += u;
            }
            if (lane < 16) wsum[lane] = t;
        }
        __syncthreads();
        const int wbase = (wave == 0) ? 0 : wsum[wave - 1];
        if (i < N_NODES) {
            const int o = carry + wbase + s - v;
            off[i] = o;
            cur[i] = o;
        }
        const int tot = wsum[15];
        __syncthreads();
        if (tid == 0) carry += tot;
        __syncthreads();
    }
    if (tid == 0) off[N_NODES] = carry;

    // graph boundaries (batch is sorted)
    if (tid <= N_GRAPHS) {
        if (tid == N_GRAPHS) { start[N_GRAPHS] = N_NODES; }
        else {
            int lo = 0, hi = N_NODES;
            while (lo < hi) { const int mid = (lo + hi) >> 1; if (batch[mid] < tid) lo = mid + 1; else hi = mid; }
            start[tid] = lo;
        }
    }
}

// light scatter: dst-sorted (src, eid) pairs only — 2.5 MB
__global__ __launch_bounds__(256) void scatter_kernel(
    const int* __restrict__ src, const int* __restrict__ dst,
    int* __restrict__ cursor, int2* __restrict__ sidx)
{
    const int e = blockIdx.x * 256 + threadIdx.x;
    if (e < N_EDGES) {
        const int p = atomicAdd(cursor + dst[e], 1);
        sidx[p] = make_int2(src[e], e);
    }
}

// ---------------------------------------------------------------------------
// agg3 v4 (measured 71 us, best so far — unchanged this round).
// out[v] = bf16( x[v] + sum_e relu(x[src] + ea@We.T + be) )
// ---------------------------------------------------------------------------
template<int IN>
__global__ __launch_bounds__(256, 4) void agg3(
    const unsigned short* __restrict__ xb,   // [M_PAD, IN] bf16
    const unsigned short* __restrict__ eah,  // [E,16] f16 (original edge order)
    const int2* __restrict__ sidx,           // (src, eid) sorted by dst
    const int* __restrict__ off,             // [N+1]
    const unsigned short* __restrict__ Weh,  // [IN,16] f16
    const float* __restrict__ be,
    unsigned short* __restrict__ out)        // [M_PAD, IN] bf16
{
    constexpr int CPL = IN / 64;             // 2 (layer1) or 4
    constexpr int XW  = CPL / 2;             // x-row dwords per lane: 1 or 2
    const int lane = threadIdx.x & 63;
    const int node = blockIdx.x * 4 + (threadIdx.x >> 6);
    if (node >= N_NODES) return;
    const int c0 = lane * CPL;
    const int zd = __builtin_amdgcn_mbcnt_lo(0u, 0u);   // divergent zero: defeats SMEM scalarization
    const u32x2* sv = (const u32x2*)sidx;

    // weights: CPL rows x 16 f16 = CPL x (u32x4 lo, u32x4 hi)
    u32x4 wlo[CPL], whi[CPL];
    float bias[CPL], acc[CPL];
#pragma unroll
    for (int j = 0; j < CPL; ++j) {
        const u32x4* wr = (const u32x4*)(Weh + (size_t)(c0 + j) * 16);
        wlo[j] = wr[0];
        whi[j] = wr[1];
        bias[j] = be[c0 + j];
        acc[j]  = 0.0f;
    }
    // pin weights + bias in VGPRs (best-effort; see v3/v4 notes)
#pragma unroll
    for (int j = 0; j < CPL; ++j) {
#pragma unroll
        for (int k = 0; k < 4; ++k) {
            { float t = __builtin_bit_cast(float, wlo[j][k]); asm("" : "+v"(t)); wlo[j][k] = __builtin_bit_cast(unsigned int, t); }
            { float t = __builtin_bit_cast(float, whi[j][k]); asm("" : "+v"(t)); whi[j][k] = __builtin_bit_cast(unsigned int, t); }
        }
        asm("" : "+v"(bias[j]));
    }

    const int p0 = __builtin_amdgcn_readfirstlane(off[node]);
    const int p1 = __builtin_amdgcn_readfirstlane(off[node + 1]);
    const int n  = p1 - p0;

    // x-row loader: always returns u32x2; CPL==2 uses only element 0
    auto ldx = [&](u32x2 id) -> u32x2 {
        const int s = (int)id[0];
        if constexpr (XW == 2) {
            return *(const u32x2*)(xb + (size_t)s * IN + c0);
        } else {
            u32x2 r;
            r[0] = *(const unsigned int*)(xb + (size_t)s * IN + c0);
            r[1] = 0u;
            return r;
        }
    };
    auto ldeaL = [&](u32x2 id) -> u32x4 {
        return ((const u32x4*)(eah + (size_t)id[1] * 16))[0];
    };
    auto ldeaH = [&](u32x2 id) -> u32x4 {
        return ((const u32x4*)(eah + (size_t)id[1] * 16))[1];
    };
    // clamped id fetch (branch-free; valid for any i when n > 0)
    auto ldid = [&](int i) -> u32x2 {
        const int q = (i < n) ? i : (n - 1);
        return sv[p0 + q + zd];
    };
    auto edge_compute = [&](u32x4 eL, u32x4 eH, u32x2 xw) {
        float m[CPL];
#pragma unroll
        for (int j = 0; j < CPL; ++j) m[j] = bias[j];
#pragma unroll
        for (int k = 0; k < 4; ++k) {
            const h2 ep = __builtin_bit_cast(h2, eL[k]);
#pragma unroll
            for (int j = 0; j < CPL; ++j)
                m[j] = DOT2(ep, __builtin_bit_cast(h2, wlo[j][k]), m[j]);
        }
#pragma unroll
        for (int k = 0; k < 4; ++k) {
            const h2 ep = __builtin_bit_cast(h2, eH[k]);
#pragma unroll
            for (int j = 0; j < CPL; ++j)
                m[j] = DOT2(ep, __builtin_bit_cast(h2, whi[j][k]), m[j]);
        }
        // add x_src (bf16 unpack: even col = word<<16, odd col = word&0xFFFF0000)
#pragma unroll
        for (int j = 0; j < CPL; ++j) {
            const unsigned int word = xw[j >> 1];
            const float xf = __builtin_bit_cast(float,
                (j & 1) ? (word & 0xFFFF0000u) : (word << 16));
            acc[j] += fmaxf(m[j] + xf, 0.0f);
        }
    };

    if (n > 0) {
        u32x2 idA = ldid(0), idB = ldid(1);
        u32x2 idC = ldid(2), idD = ldid(3);
        u32x4 eLA = ldeaL(idA), eHA = ldeaH(idA); u32x2 xA = ldx(idA);
        u32x4 eLB = ldeaL(idB), eHB = ldeaH(idB); u32x2 xB = ldx(idB);

        int i = 0;
        for (; i + 2 <= n; i += 2) {
            edge_compute(eLA, eHA, xA);
            eLA = ldeaL(idC); eHA = ldeaH(idC); xA = ldx(idC);   // data for i+2
            idC = ldid(i + 4);
            edge_compute(eLB, eHB, xB);
            eLB = ldeaL(idD); eHB = ldeaH(idD); xB = ldx(idD);   // data for i+3
            idD = ldid(i + 5);
        }
        if (i < n) edge_compute(eLA, eHA, xA);                   // odd tail
    }

    // out[node] = bf16(x[node] + acc), packed manually
    if constexpr (XW == 2) {
        const u32x2 xs = *(const u32x2*)(xb + (size_t)node * IN + c0);
        const float x0 = __builtin_bit_cast(float, xs[0] << 16);
        const float x1 = __builtin_bit_cast(float, xs[0] & 0xFFFF0000u);
        const float x2 = __builtin_bit_cast(float, xs[1] << 16);
        const float x3 = __builtin_bit_cast(float, xs[1] & 0xFFFF0000u);
        u32x2 o;
        o[0] = (unsigned)f2bf(x0 + acc[0]) | ((unsigned)f2bf(x1 + acc[1]) << 16);
        o[1] = (unsigned)f2bf(x2 + acc[2]) | ((unsigned)f2bf(x3 + acc[3]) << 16);
        *(u32x2*)(out + (size_t)node * IN + c0) = o;
    } else {
        const unsigned int xs = *(const unsigned int*)(xb + (size_t)node * IN + c0);
        const float x0 = __builtin_bit_cast(float, xs << 16);
        const float x1 = __builtin_bit_cast(float, xs & 0xFFFF0000u);
        const unsigned int o =
            (unsigned)f2bf(x0 + acc[0]) | ((unsigned)f2bf(x1 + acc[1]) << 16);
        *(unsigned int*)(out + (size_t)node * IN + c0) = o;
    }
}

// ---------------------------------------------------------------------------
// B-in-register streaming GEMM v2 (best measured config, R9):
// grid (313,2), 4 waves/block, wave owns 32 cols with K resident in regs;
// 4 chunks of 16 rows with 2-deep prefetch. No LDS, no barriers.
// EPI 0: BN(eval)+relu -> bf16 (all rows)   EPI 1: bias+relu (rows < N)
// ---------------------------------------------------------------------------
template<int K, int EPI>
__global__ __launch_bounds__(256) void gemm_breg2(
    const unsigned short* __restrict__ A,    // [M_PAD, K]
    const unsigned short* __restrict__ W,    // [256, K]
    const float* __restrict__ bias,
    const float* __restrict__ gsc, const float* __restrict__ bsh,
    unsigned short* __restrict__ out)        // [M_PAD, 256]
{
    constexpr int KC = K / 32;               // 4 or 8 k-chunks
    const int w = threadIdx.x >> 6, lane = threadIdx.x & 63;
    const int lm = lane & 15, lq = lane >> 4;
    const int n0 = (blockIdx.y * 4 + w) * 32;
    const int m0 = blockIdx.x * 64;

    // B resident in registers
    bf16x8 B0[KC], B1[KC];
    {
        const unsigned short* Wp0 = W + (size_t)(n0 + lm) * K + lq * 8;
        const unsigned short* Wp1 = W + (size_t)(n0 + 16 + lm) * K + lq * 8;
#pragma unroll
        for (int c = 0; c < KC; ++c) {
            B0[c] = *(const bf16x8*)(Wp0 + c * 32);
            B1[c] = *(const bf16x8*)(Wp1 + c * 32);
        }
    }

    const float inv = rsqrtf(1.0f + 1e-5f);
    const float bc0 = bias[n0 + lm],      bc1 = bias[n0 + 16 + lm];
    const float gc0 = (EPI == 0) ? gsc[n0 + lm]      : 0.0f;
    const float gc1 = (EPI == 0) ? gsc[n0 + 16 + lm] : 0.0f;
    const float sc0 = (EPI == 0) ? bsh[n0 + lm]      : 0.0f;
    const float sc1 = (EPI == 0) ? bsh[n0 + 16 + lm] : 0.0f;

    bf16x8 aC[KC], aN[KC];
    {
        const unsigned short* Ap = A + (size_t)(m0 + lm) * K + lq * 8;
#pragma unroll
        for (int c = 0; c < KC; ++c) aC[c] = *(const bf16x8*)(Ap + c * 32);
    }

#pragma unroll
    for (int ch = 0; ch < 4; ++ch) {
        if (ch < 3) {
            const unsigned short* Ap = A + (size_t)(m0 + (ch + 1) * 16 + lm) * K + lq * 8;
#pragma unroll
            for (int c = 0; c < KC; ++c) aN[c] = *(const bf16x8*)(Ap + c * 32);
        }

        f32x4 acc0 = (f32x4){0.f, 0.f, 0.f, 0.f};
        f32x4 acc1 = (f32x4){0.f, 0.f, 0.f, 0.f};
#pragma unroll
        for (int c = 0; c < KC; ++c) {
            acc0 = __builtin_amdgcn_mfma_f32_16x16x32_bf16(aC[c], B0[c], acc0, 0, 0, 0);
            acc1 = __builtin_amdgcn_mfma_f32_16x16x32_bf16(aC[c], B1[c], acc1, 0, 0, 0);
        }

        const int mr = m0 + ch * 16;
#pragma unroll
        for (int r = 0; r < 4; ++r) {
            const int row = mr + lq * 4 + r;
            if (EPI == 1 && row >= N_NODES) continue;
            float v0 = acc0[r] + bc0;
            float v1 = acc1[r] + bc1;
            if (EPI == 0) {
                v0 = fmaxf(v0 * inv * gc0 + sc0, 0.0f);
                v1 = fmaxf(v1 * inv * gc1 + sc1, 0.0f);
            } else {
                v0 = fmaxf(v0, 0.0f);
                v1 = fmaxf(v1, 0.0f);
            }
            out[(size_t)row * H + n0 + lm]      = f2bf(v0);
            out[(size_t)row * H + n0 + 16 + lm] = f2bf(v1);
        }

#pragma unroll
        for (int c = 0; c < KC; ++c) aC[c] = aN[c];
    }
}

// ---------------------------------------------------------------------------
// Parallel mean-pool: grid (192, RSPLIT). Block (g, layer, chunk) reduces
// ~rows/RSPLIT rows and atomicAdds one partial per column into pool.
// ---------------------------------------------------------------------------
#define RSPLIT 6
__global__ __launch_bounds__(256) void pool2(
    const unsigned short* __restrict__ h1, const unsigned short* __restrict__ h2,
    const unsigned short* __restrict__ h3, const int* __restrict__ start,
    float* __restrict__ pool)
{
    const int g = blockIdx.x & 63, layer = blockIdx.x >> 6;
    const unsigned short* h = (layer == 0) ? h1 : (layer == 1) ? h2 : h3;
    const int r0 = start[g], r1 = start[g + 1];
    const int nr = r1 - r0;
    if (nr <= 0) return;
    const int chunk = (nr + RSPLIT - 1) / RSPLIT;
    const int rs = r0 + blockIdx.y * chunk;
    const int re = (rs + chunk < r1) ? rs + chunk : r1;
    if (rs >= re) return;

    const int c = threadIdx.x;
    float s0 = 0.f, s1 = 0.f, s2 = 0.f, s3 = 0.f;
    int r = rs;
    for (; r + 4 <= re; r += 4) {
        s0 += bf2f(h[(size_t)(r + 0) * H + c]);
        s1 += bf2f(h[(size_t)(r + 1) * H + c]);
        s2 += bf2f(h[(size_t)(r + 2) * H + c]);
        s3 += bf2f(h[(size_t)(r + 3) * H + c]);
    }
    for (; r < re; ++r) s0 += bf2f(h[(size_t)r * H + c]);
    atomicAdd(&pool[(size_t)g * POOL_W + layer * 256 + c], s0 + s1 + s2 + s3);
}

// ---------------------------------------------------------------------------
// FC head v2 — final_kernel post-mortem (74 us, occupancy 2.76%, VALUBusy
// 1.9%): 64 blocks on 256 CUs, and each thread read its own L1w row (lane
// addresses stride 3 KB -> every float4 load = 64 cache-line transactions,
// no latency hiding). Replacement: grid (64 graphs x 12 chunks) = 768
// blocks; per wave one output at a time with the 768-dot LANE-PARALLEL
// (3 coalesced float4 per lane vs register-hoisted p fragments) + 6-step
// shfl_xor reduce. OUT=1 lets FC2 fold in: lane0 accumulates
// relu(acc+L1b)*L2w and atomicAdds one scalar per wave -> no f1 buffer.
// ---------------------------------------------------------------------------
__global__ __launch_bounds__(256) void fc_head(
    const float* __restrict__ pool, const int* __restrict__ start,
    const float* __restrict__ L1w, const float* __restrict__ L1b,
    const float* __restrict__ L2w, float* __restrict__ gsum)
{
    const int g = blockIdx.x;
    __shared__ float p[POOL_W];

    const float rc = 1.0f / fmaxf((float)(start[g + 1] - start[g]), 1.0f);
    for (int i = threadIdx.x; i < POOL_W; i += 256)
        p[i] = pool[(size_t)g * POOL_W + i] * rc;
    __syncthreads();

    const int wv = threadIdx.x >> 6, lane = threadIdx.x & 63;
    const float4* p4 = (const float4*)p;
    // p fragments hoisted to registers (constant across the 16 outputs)
    const float4 pa = p4[lane], pb = p4[lane + 64], pc = p4[lane + 128];

    const int ob = blockIdx.y * 64 + wv * 16;
    float part = 0.0f;
#pragma unroll 4
    for (int t = 0; t < 16; ++t) {
        const int o = ob + t;
        const float4* wr = (const float4*)(L1w + (size_t)o * POOL_W);
        const float4 a = wr[lane], b = wr[lane + 64], c = wr[lane + 128];
        float acc = a.x * pa.x + a.y * pa.y + a.z * pa.z + a.w * pa.w
                  + b.x * pb.x + b.y * pb.y + b.z * pb.z + b.w * pb.w
                  + c.x * pc.x + c.y * pc.y + c.z * pc.z + c.w * pc.w;
#pragma unroll
        for (int off = 32; off > 0; off >>= 1) acc += __shfl_xor(acc, off);
        if (lane == 0) part += fmaxf(acc + L1b[o], 0.0f) * L2w[o];
    }
    if (lane == 0) atomicAdd(&gsum[g], part);
}

__global__ __launch_bounds__(64) void sig_kernel(
    const float* __restrict__ gsum, const float* __restrict__ L2b,
    float* __restrict__ out)
{
    const int g = threadIdx.x;
    if (g < N_GRAPHS) out[g] = 1.0f / (1.0f + expf(-(gsum[g] + L2b[0])));
}

// ---------------------------------------------------------------------------
extern "C" void kernel_launch(void* const* d_in, const int* in_sizes, int n_in,
                              void* d_out, int out_size, void* d_ws, size_t ws_size,
                              hipStream_t stream)
{
    const float* x     = (const float*)d_in[0];
    const float* ea    = (const float*)d_in[1];
    const int*   src   = (const int*)d_in[2];
    const int*   dst   = (const int*)d_in[3];
    const int*   batch = (const int*)d_in[4];

    const float* We[3]; const float* be[3]; const float* Wa[3]; const float* ba[3];
    const float* gg[3]; const float* bt[3]; const float* Wb[3]; const float* bb[3];
    for (int l = 0; l < 3; ++l) {
        const int o = 5 + 8 * l;
        We[l] = (const float*)d_in[o + 0]; be[l] = (const float*)d_in[o + 1];
        Wa[l] = (const float*)d_in[o + 2]; ba[l] = (const float*)d_in[o + 3];
        gg[l] = (const float*)d_in[o + 4]; bt[l] = (const float*)d_in[o + 5];
        Wb[l] = (const float*)d_in[o + 6]; bb[l] = (const float*)d_in[o + 7];
    }
    const float* L1w = (const float*)d_in[29];
    const float* L1b = (const float*)d_in[30];
    const float* L2w = (const float*)d_in[31];
    const float* L2b = (const float*)d_in[32];

    // ---- workspace layout ----
    float* pool   = (float*)d_ws;                              // 64*768
    float* gsum   = pool + (size_t)N_GRAPHS * POOL_W;          // 64 (zeroed with pool)
    int*   deg    = (int*)(gsum + N_GRAPHS);                   // N
    int*   off    = deg + N_NODES;                             // N+1
    int*   cursor = off + N_NODES + 1;                         // N
    int*   start  = cursor + N_NODES;                          // 72
    int2*  sidx   = (int2*)((((uintptr_t)(start + 72)) + 15) & ~(uintptr_t)15);  // E
    unsigned short* xb = (unsigned short*)((((uintptr_t)(sidx + N_EDGES)) + 15) & ~(uintptr_t)15);
    unsigned short* u  = xb + (size_t)M_PAD * DIN;             // [M_PAD,256] (layer1 uses 128)
    unsigned short* tT = u  + (size_t)M_PAD * H;               // [M_PAD,256] intermediate
    unsigned short* h1 = tT + (size_t)M_PAD * H;
    unsigned short* h2 = h1 + (size_t)M_PAD * H;
    unsigned short* h3 = h2 + (size_t)M_PAD * H;
    unsigned short* wbf[6];
    wbf[0] = h3 + (size_t)M_PAD * H;                           // Wa1 [256,128]
    wbf[1] = wbf[0] + H * DIN;
    for (int i = 2; i < 6; ++i) wbf[i] = wbf[i - 1] + H * H;
    unsigned short* eah = wbf[5] + H * H;                      // [E,16] f16
    unsigned short* weh[3];
    weh[0] = eah + (size_t)N_EDGES * 16;                       // We1 [128,16] f16
    weh[1] = weh[0] + DIN * 16;                                // We2 [256,16] f16
    weh[2] = weh[1] + H * 16;                                  // We3 [256,16] f16

    // batched converts + deg/pool+gsum zeroing in one launch (13 jobs)
    CvtJobs jobs;
    jobs.j[0]  = { x,       xb,                    N_NODES * DIN / 4,       0 };
    jobs.j[1]  = { Wa[0],   wbf[0],                H * DIN / 4,             0 };
    jobs.j[2]  = { Wb[0],   wbf[1],                H * H / 4,               0 };
    jobs.j[3]  = { Wa[1],   wbf[2],                H * H / 4,               0 };
    jobs.j[4]  = { Wb[1],   wbf[3],                H * H / 4,               0 };
    jobs.j[5]  = { Wa[2],   wbf[4],                H * H / 4,               0 };
    jobs.j[6]  = { Wb[2],   wbf[5],                H * H / 4,               0 };
    jobs.j[7]  = { nullptr, (unsigned short*)deg,  N_NODES * 4 / 8,         2 };  // zero N ints
    jobs.j[8]  = { nullptr, (unsigned short*)pool, (N_GRAPHS * POOL_W + N_GRAPHS) * 4 / 8, 2 }; // zero pool+gsum
    jobs.j[9]  = { ea,      eah,                   N_EDGES * 16 / 4,        1 };  // ea -> f16
    jobs.j[10] = { We[0],   weh[0],                DIN * 16 / 4,            1 };
    jobs.j[11] = { We[1],   weh[1],                H * 16 / 4,              1 };
    jobs.j[12] = { We[2],   weh[2],                H * 16 / 4,              1 };
    cvt_all<<<dim3(320, 13), 256, 0, stream>>>(jobs);

    // CSR + graph boundaries
    hist_kernel<<<(N_EDGES + 255) / 256, 256, 0, stream>>>(dst, deg);
    scan_kernel<<<1, 1024, 0, stream>>>(deg, off, cursor, batch, start);
    scatter_kernel<<<(N_EDGES + 255) / 256, 256, 0, stream>>>(src, dst, cursor, sidx);

    const int  agrid = (N_NODES + 3) / 4;       // agg3: 1 node/wave
    const dim3 ggrid(M_PAD / 64, 2);            // (313, 2)

    // ---- layer 1 (in=128) ----
    agg3<DIN><<<agrid, 256, 0, stream>>>(xb, eah, sidx, off, weh[0], be[0], u);
    gemm_breg2<DIN, 0><<<ggrid, 256, 0, stream>>>(u, wbf[0], ba[0], gg[0], bt[0], tT);
    gemm_breg2<H,   1><<<ggrid, 256, 0, stream>>>(tT, wbf[1], bb[0], nullptr, nullptr, h1);
    // ---- layer 2 ----
    agg3<H><<<agrid, 256, 0, stream>>>(h1, eah, sidx, off, weh[1], be[1], u);
    gemm_breg2<H, 0><<<ggrid, 256, 0, stream>>>(u, wbf[2], ba[1], gg[1], bt[1], tT);
    gemm_breg2<H, 1><<<ggrid, 256, 0, stream>>>(tT, wbf[3], bb[1], nullptr, nullptr, h2);
    // ---- layer 3 ----
    agg3<H><<<agrid, 256, 0, stream>>>(h2, eah, sidx, off, weh[2], be[2], u);
    gemm_breg2<H, 0><<<ggrid, 256, 0, stream>>>(u, wbf[4], ba[2], gg[2], bt[2], tT);
    gemm_breg2<H, 1><<<ggrid, 256, 0, stream>>>(tT, wbf[5], bb[2], nullptr, nullptr, h3);

    // parallel mean-pool + head
    pool2<<<dim3(3 * N_GRAPHS, RSPLIT), 256, 0, stream>>>(h1, h2, h3, start, pool);
    fc_head<<<dim3(N_GRAPHS, POOL_W / 64), 256, 0, stream>>>(pool, start, L1w, L1b, L2w, gsum);
    sig_kernel<<<1, 64, 0, stream>>>(gsum, L2b, (float*)d_out);
}

// Round 5
// 518.285 us; speedup vs baseline: 1.1615x; 1.0227x over previous
//
#include <hip/hip_runtime.h>
#include <math.h>
#include <stdint.h>

#define N_NODES 20000
#define M_PAD 20032            // 313 * 64
#define N_EDGES 320000
#define N_GRAPHS 64
#define DIN 128
#define H 256
#define POOL_W 768

typedef __attribute__((ext_vector_type(8))) short bf16x8;   // 8 bf16 = 4 VGPRs
typedef __attribute__((ext_vector_type(4))) float f32x4;
typedef __attribute__((ext_vector_type(4))) unsigned int u32x4;
typedef __attribute__((ext_vector_type(2))) unsigned int u32x2;
typedef _Float16 h2 __attribute__((ext_vector_type(2)));    // packed f16 pair (1 VGPR)

__device__ __forceinline__ unsigned short f2bf(float f) {
    unsigned u = __builtin_bit_cast(unsigned, f);
    u += 0x7FFFu + ((u >> 16) & 1u);          // round-to-nearest-even
    return (unsigned short)(u >> 16);
}
__device__ __forceinline__ float bf2f(unsigned short u) {
    return __builtin_bit_cast(float, (unsigned)u << 16);
}
__device__ __forceinline__ unsigned short f2h(float f) {
    const _Float16 h = (_Float16)f;
    return __builtin_bit_cast(unsigned short, h);
}

#if __has_builtin(__builtin_amdgcn_fdot2)
#define DOT2(a, b, c) __builtin_amdgcn_fdot2((a), (b), (c), false)
#else
__device__ __forceinline__ float dot2_fallback(h2 a, h2 b, float c) {
    return fmaf((float)a.x, (float)b.x, fmaf((float)a.y, (float)b.y, c));
}
#define DOT2(a, b, c) dot2_fallback((a), (b), (c))
#endif

// ---------------------------------------------------------------------------
// Batched converts + zero jobs: 12 jobs, one launch.
// mode 0: fp32 -> bf16   mode 1: fp32 -> f16   mode 2: zero fill
// ---------------------------------------------------------------------------
struct CvtJob  { const float* s; unsigned short* d; int n4; int mode; };
struct CvtJobs { CvtJob j[12]; };

__global__ __launch_bounds__(256) void cvt_all(CvtJobs jobs)
{
    const CvtJob J = jobs.j[blockIdx.y];
    if (J.mode == 2) {
        const ushort4 z = {0, 0, 0, 0};
        for (int i = blockIdx.x * 256 + threadIdx.x; i < J.n4; i += gridDim.x * 256)
            ((ushort4*)J.d)[i] = z;
        return;
    }
    if (J.mode == 1) {
        for (int i = blockIdx.x * 256 + threadIdx.x; i < J.n4; i += gridDim.x * 256) {
            const float4 v = ((const float4*)J.s)[i];
            ushort4 r;
            r.x = f2h(v.x); r.y = f2h(v.y); r.z = f2h(v.z); r.w = f2h(v.w);
            ((ushort4*)J.d)[i] = r;
        }
        return;
    }
    for (int i = blockIdx.x * 256 + threadIdx.x; i < J.n4; i += gridDim.x * 256) {
        const float4 v = ((const float4*)J.s)[i];
        ushort4 r;
        r.x = f2bf(v.x); r.y = f2bf(v.y); r.z = f2bf(v.z); r.w = f2bf(v.w);
        ((ushort4*)J.d)[i] = r;
    }
}

// ---------------------------------------------------------------------------
// CSR build
// ---------------------------------------------------------------------------
__global__ __launch_bounds__(256) void hist_kernel(const int* __restrict__ dst,
                                                   int* __restrict__ deg)
{
    const int i = blockIdx.x * 256 + threadIdx.x;
    if (i < N_EDGES) atomicAdd(deg + dst[i], 1);
}

// shfl scan; writes off and cursor; tail threads also compute graph starts
__global__ __launch_bounds__(1024) void scan_kernel(const int* __restrict__ deg,
                                                    int* __restrict__ off,
                                                    int* __restrict__ cur,
                                                    const int* __restrict__ batch,
                                                    int* __restrict__ start)
{
    __shared__ int wsum[16];
    __shared__ int carry;
    const int tid = threadIdx.x, wave = tid >> 6, lane = tid & 63;
    if (tid == 0) carry = 0;
    __syncthreads();
    for (int base = 0; base < N_NODES; base += 1024) {
        const int i = base + tid;
        const int v = (i < N_NODES) ? deg[i] : 0;
        int s = v;
#pragma unroll
        for (int d = 1; d < 64; d <<= 1) {
            const int t = __shfl_up(s, d);
            if (lane >= d) s += t;
        }
        if (lane == 63) wsum[wave] = s;
        __syncthreads();
        if (wave == 0) {
            int t = (lane < 16) ? wsum[lane] : 0;
#pragma unroll
            for (int d = 1; d < 16; d <<= 1) {
                const int u = __shfl_up(t, d);
                if (lane >= d) t += u;
            }
            if (lane < 16) wsum[lane] = t;
        }
        __syncthreads();
        const int wbase = (wave == 0) ? 0 : wsum[wave - 1];
        if (i < N_NODES) {
            const int o = carry + wbase + s - v;
            off[i] = o;
            cur[i] = o;
        }
        const int tot = wsum[15];
        __syncthreads();
        if (tid == 0) carry += tot;
        __syncthreads();
    }
    if (tid == 0) off[N_NODES] = carry;

    // graph boundaries (batch is sorted)
    if (tid <= N_GRAPHS) {
        if (tid == N_GRAPHS) { start[N_GRAPHS] = N_NODES; }
        else {
            int lo = 0, hi = N_NODES;
            while (lo < hi) { const int mid = (lo + hi) >> 1; if (batch[mid] < tid) lo = mid + 1; else hi = mid; }
            start[tid] = lo;
        }
    }
}

// scatter v2: build CSR-sorted src ids AND CSR-sorted f16 edge features in
// one pass (reads original fp32 ea; the edge-order eah buffer is gone).
// agg3's ea reads become LINEAR: no eid indirection, prefetchable deep.
__global__ __launch_bounds__(256) void scatter_kernel(
    const int* __restrict__ src, const int* __restrict__ dst,
    const float* __restrict__ ea, int* __restrict__ cursor,
    int* __restrict__ ssrc, unsigned short* __restrict__ eas)
{
    const int e = blockIdx.x * 256 + threadIdx.x;
    if (e < N_EDGES) {
        const int p = atomicAdd(cursor + dst[e], 1);
        ssrc[p] = src[e];
        const float4* er = (const float4*)(ea + (size_t)e * 16);
        unsigned short* dr = eas + (size_t)p * 16;
        ushort4* d4 = (ushort4*)dr;
#pragma unroll
        for (int q = 0; q < 4; ++q) {
            const float4 v = er[q];
            ushort4 r;
            r.x = f2h(v.x); r.y = f2h(v.y); r.z = f2h(v.z); r.w = f2h(v.w);
            d4[q] = r;
        }
    }
}

// ---------------------------------------------------------------------------
// agg3 v5 — v4 post-mortem: VGPR=28 again (non-volatile asm pin is sinkable)
// and the 2-deep pipeline leaves ~600cy avg gather latency exposed.
// Changes: (1) ea is now CSR-SORTED (eas) -> linear reads, no eid chain;
// sidx(int2) -> ssrc(int); (2) depth-4 in-place pipeline (A-D), src ids
// prefetched 8 ahead, clamped branch-free; (3) asm VOLATILE weight pin —
// volatile can't be sunk into the loop (execution count would change).
// out[v] = bf16( x[v] + sum_e relu(x[src] + ea@We.T + be) )
// ---------------------------------------------------------------------------
template<int IN>
__global__ __launch_bounds__(256, 4) void agg3(
    const unsigned short* __restrict__ xb,   // [M_PAD, IN] bf16
    const unsigned short* __restrict__ eas,  // [E,16] f16, CSR order
    const int* __restrict__ ssrc,            // [E] src, CSR order
    const int* __restrict__ off,             // [N+1]
    const unsigned short* __restrict__ Weh,  // [IN,16] f16
    const float* __restrict__ be,
    unsigned short* __restrict__ out)        // [M_PAD, IN] bf16
{
    constexpr int CPL = IN / 64;             // 2 (layer1) or 4
    constexpr int XW  = CPL / 2;             // x-row dwords per lane: 1 or 2
    const int lane = threadIdx.x & 63;
    const int node = blockIdx.x * 4 + (threadIdx.x >> 6);
    if (node >= N_NODES) return;
    const int c0 = lane * CPL;
    const int zd = __builtin_amdgcn_mbcnt_lo(0u, 0u);   // divergent zero: defeats SMEM scalarization

    // weights: CPL rows x 16 f16 = CPL x (u32x4 lo, u32x4 hi) — pinned resident
    u32x4 wlo[CPL], whi[CPL];
    float bias[CPL], acc[CPL];
#pragma unroll
    for (int j = 0; j < CPL; ++j) {
        const u32x4* wr = (const u32x4*)(Weh + (size_t)(c0 + j) * 16);
        wlo[j] = wr[0];
        whi[j] = wr[1];
        bias[j] = be[c0 + j];
        acc[j]  = 0.0f;
    }
    // VOLATILE pin: cannot be sunk/duplicated into the loop.
#pragma unroll
    for (int j = 0; j < CPL; ++j) {
#pragma unroll
        for (int k = 0; k < 4; ++k) {
            { float t = __builtin_bit_cast(float, wlo[j][k]); asm volatile("" : "+v"(t)); wlo[j][k] = __builtin_bit_cast(unsigned int, t); }
            { float t = __builtin_bit_cast(float, whi[j][k]); asm volatile("" : "+v"(t)); whi[j][k] = __builtin_bit_cast(unsigned int, t); }
        }
        asm volatile("" : "+v"(bias[j]));
    }

    const int p0 = __builtin_amdgcn_readfirstlane(off[node]);
    const int p1 = __builtin_amdgcn_readfirstlane(off[node + 1]);
    const int n  = p1 - p0;

    auto ldsrc = [&](int i) -> int {          // clamped, divergent (vector load)
        const int q = (i < n) ? i : (n - 1);
        return ssrc[p0 + q + zd];
    };
    auto ldeL = [&](int i) -> u32x4 {         // linear CSR read, clamped
        const int q = (i < n) ? i : (n - 1);
        return ((const u32x4*)(eas + (size_t)(p0 + q + zd) * 16))[0];
    };
    auto ldeH = [&](int i) -> u32x4 {
        const int q = (i < n) ? i : (n - 1);
        return ((const u32x4*)(eas + (size_t)(p0 + q + zd) * 16))[1];
    };
    auto ldx = [&](int s) -> u32x2 {
        if constexpr (XW == 2) {
            return *(const u32x2*)(xb + (size_t)s * IN + c0);
        } else {
            u32x2 r;
            r[0] = *(const unsigned int*)(xb + (size_t)s * IN + c0);
            r[1] = 0u;
            return r;
        }
    };
    auto edge_compute = [&](u32x4 eL, u32x4 eH, u32x2 xw) {
        float m[CPL];
#pragma unroll
        for (int j = 0; j < CPL; ++j) m[j] = bias[j];
#pragma unroll
        for (int k = 0; k < 4; ++k) {
            const h2 ep = __builtin_bit_cast(h2, eL[k]);
#pragma unroll
            for (int j = 0; j < CPL; ++j)
                m[j] = DOT2(ep, __builtin_bit_cast(h2, wlo[j][k]), m[j]);
        }
#pragma unroll
        for (int k = 0; k < 4; ++k) {
            const h2 ep = __builtin_bit_cast(h2, eH[k]);
#pragma unroll
            for (int j = 0; j < CPL; ++j)
                m[j] = DOT2(ep, __builtin_bit_cast(h2, whi[j][k]), m[j]);
        }
        // add x_src (bf16 unpack: even col = word<<16, odd col = word&0xFFFF0000)
#pragma unroll
        for (int j = 0; j < CPL; ++j) {
            const unsigned int word = xw[j >> 1];
            const float xf = __builtin_bit_cast(float,
                (j & 1) ? (word & 0xFFFF0000u) : (word << 16));
            acc[j] += fmaxf(m[j] + xf, 0.0f);
        }
    };

    if (n > 0) {
        int sA = ldsrc(0), sB = ldsrc(1), sC = ldsrc(2), sD = ldsrc(3);
        u32x4 eLA = ldeL(0), eHA = ldeH(0);
        u32x4 eLB = ldeL(1), eHB = ldeH(1);
        u32x4 eLC = ldeL(2), eHC = ldeH(2);
        u32x4 eLD = ldeL(3), eHD = ldeH(3);
        u32x2 xA = ldx(sA), xB = ldx(sB), xC = ldx(sC), xD = ldx(sD);
        sA = ldsrc(4); sB = ldsrc(5); sC = ldsrc(6); sD = ldsrc(7);

        int i = 0;
        for (; i + 4 <= n; i += 4) {
            edge_compute(eLA, eHA, xA);
            eLA = ldeL(i + 4); eHA = ldeH(i + 4); xA = ldx(sA); sA = ldsrc(i + 8);
            edge_compute(eLB, eHB, xB);
            eLB = ldeL(i + 5); eHB = ldeH(i + 5); xB = ldx(sB); sB = ldsrc(i + 9);
            edge_compute(eLC, eHC, xC);
            eLC = ldeL(i + 6); eHC = ldeH(i + 6); xC = ldx(sC); sC = ldsrc(i + 10);
            edge_compute(eLD, eHD, xD);
            eLD = ldeL(i + 7); eHD = ldeH(i + 7); xD = ldx(sD); sD = ldsrc(i + 11);
        }
        if (i < n)     edge_compute(eLA, eHA, xA);
        if (i + 1 < n) edge_compute(eLB, eHB, xB);
        if (i + 2 < n) edge_compute(eLC, eHC, xC);
    }

    // out[node] = bf16(x[node] + acc), packed manually
    if constexpr (XW == 2) {
        const u32x2 xs = *(const u32x2*)(xb + (size_t)node * IN + c0);
        const float x0 = __builtin_bit_cast(float, xs[0] << 16);
        const float x1 = __builtin_bit_cast(float, xs[0] & 0xFFFF0000u);
        const float x2 = __builtin_bit_cast(float, xs[1] << 16);
        const float x3 = __builtin_bit_cast(float, xs[1] & 0xFFFF0000u);
        u32x2 o;
        o[0] = (unsigned)f2bf(x0 + acc[0]) | ((unsigned)f2bf(x1 + acc[1]) << 16);
        o[1] = (unsigned)f2bf(x2 + acc[2]) | ((unsigned)f2bf(x3 + acc[3]) << 16);
        *(u32x2*)(out + (size_t)node * IN + c0) = o;
    } else {
        const unsigned int xs = *(const unsigned int*)(xb + (size_t)node * IN + c0);
        const float x0 = __builtin_bit_cast(float, xs << 16);
        const float x1 = __builtin_bit_cast(float, xs & 0xFFFF0000u);
        const unsigned int o =
            (unsigned)f2bf(x0 + acc[0]) | ((unsigned)f2bf(x1 + acc[1]) << 16);
        *(unsigned int*)(out + (size_t)node * IN + c0) = o;
    }
}

// ---------------------------------------------------------------------------
// B-in-register streaming GEMM v2 (best measured config, R9):
// grid (313,2), 4 waves/block, wave owns 32 cols with K resident in regs;
// 4 chunks of 16 rows with 2-deep prefetch. No LDS, no barriers.
// EPI 0: BN(eval)+relu -> bf16 (all rows)   EPI 1: bias+relu (rows < N)
// ---------------------------------------------------------------------------
template<int K, int EPI>
__global__ __launch_bounds__(256) void gemm_breg2(
    const unsigned short* __restrict__ A,    // [M_PAD, K]
    const unsigned short* __restrict__ W,    // [256, K]
    const float* __restrict__ bias,
    const float* __restrict__ gsc, const float* __restrict__ bsh,
    unsigned short* __restrict__ out)        // [M_PAD, 256]
{
    constexpr int KC = K / 32;               // 4 or 8 k-chunks
    const int w = threadIdx.x >> 6, lane = threadIdx.x & 63;
    const int lm = lane & 15, lq = lane >> 4;
    const int n0 = (blockIdx.y * 4 + w) * 32;
    const int m0 = blockIdx.x * 64;

    // B resident in registers
    bf16x8 B0[KC], B1[KC];
    {
        const unsigned short* Wp0 = W + (size_t)(n0 + lm) * K + lq * 8;
        const unsigned short* Wp1 = W + (size_t)(n0 + 16 + lm) * K + lq * 8;
#pragma unroll
        for (int c = 0; c < KC; ++c) {
            B0[c] = *(const bf16x8*)(Wp0 + c * 32);
            B1[c] = *(const bf16x8*)(Wp1 + c * 32);
        }
    }

    const float inv = rsqrtf(1.0f + 1e-5f);
    const float bc0 = bias[n0 + lm],      bc1 = bias[n0 + 16 + lm];
    const float gc0 = (EPI == 0) ? gsc[n0 + lm]      : 0.0f;
    const float gc1 = (EPI == 0) ? gsc[n0 + 16 + lm] : 0.0f;
    const float sc0 = (EPI == 0) ? bsh[n0 + lm]      : 0.0f;
    const float sc1 = (EPI == 0) ? bsh[n0 + 16 + lm] : 0.0f;

    bf16x8 aC[KC], aN[KC];
    {
        const unsigned short* Ap = A + (size_t)(m0 + lm) * K + lq * 8;
#pragma unroll
        for (int c = 0; c < KC; ++c) aC[c] = *(const bf16x8*)(Ap + c * 32);
    }

#pragma unroll
    for (int ch = 0; ch < 4; ++ch) {
        if (ch < 3) {
            const unsigned short* Ap = A + (size_t)(m0 + (ch + 1) * 16 + lm) * K + lq * 8;
#pragma unroll
            for (int c = 0; c < KC; ++c) aN[c] = *(const bf16x8*)(Ap + c * 32);
        }

        f32x4 acc0 = (f32x4){0.f, 0.f, 0.f, 0.f};
        f32x4 acc1 = (f32x4){0.f, 0.f, 0.f, 0.f};
#pragma unroll
        for (int c = 0; c < KC; ++c) {
            acc0 = __builtin_amdgcn_mfma_f32_16x16x32_bf16(aC[c], B0[c], acc0, 0, 0, 0);
            acc1 = __builtin_amdgcn_mfma_f32_16x16x32_bf16(aC[c], B1[c], acc1, 0, 0, 0);
        }

        const int mr = m0 + ch * 16;
#pragma unroll
        for (int r = 0; r < 4; ++r) {
            const int row = mr + lq * 4 + r;
            if (EPI == 1 && row >= N_NODES) continue;
            float v0 = acc0[r] + bc0;
            float v1 = acc1[r] + bc1;
            if (EPI == 0) {
                v0 = fmaxf(v0 * inv * gc0 + sc0, 0.0f);
                v1 = fmaxf(v1 * inv * gc1 + sc1, 0.0f);
            } else {
                v0 = fmaxf(v0, 0.0f);
                v1 = fmaxf(v1, 0.0f);
            }
            out[(size_t)row * H + n0 + lm]      = f2bf(v0);
            out[(size_t)row * H + n0 + 16 + lm] = f2bf(v1);
        }

#pragma unroll
        for (int c = 0; c < KC; ++c) aC[c] = aN[c];
    }
}

// ---------------------------------------------------------------------------
// Parallel mean-pool: grid (192, RSPLIT). Block (g, layer, chunk) reduces
// ~rows/RSPLIT rows and atomicAdds one partial per column into pool.
// ---------------------------------------------------------------------------
#define RSPLIT 6
__global__ __launch_bounds__(256) void pool2(
    const unsigned short* __restrict__ h1, const unsigned short* __restrict__ h2,
    const unsigned short* __restrict__ h3, const int* __restrict__ start,
    float* __restrict__ pool)
{
    const int g = blockIdx.x & 63, layer = blockIdx.x >> 6;
    const unsigned short* h = (layer == 0) ? h1 : (layer == 1) ? h2 : h3;
    const int r0 = start[g], r1 = start[g + 1];
    const int nr = r1 - r0;
    if (nr <= 0) return;
    const int chunk = (nr + RSPLIT - 1) / RSPLIT;
    const int rs = r0 + blockIdx.y * chunk;
    const int re = (rs + chunk < r1) ? rs + chunk : r1;
    if (rs >= re) return;

    const int c = threadIdx.x;
    float s0 = 0.f, s1 = 0.f, s2 = 0.f, s3 = 0.f;
    int r = rs;
    for (; r + 4 <= re; r += 4) {
        s0 += bf2f(h[(size_t)(r + 0) * H + c]);
        s1 += bf2f(h[(size_t)(r + 1) * H + c]);
        s2 += bf2f(h[(size_t)(r + 2) * H + c]);
        s3 += bf2f(h[(size_t)(r + 3) * H + c]);
    }
    for (; r < re; ++r) s0 += bf2f(h[(size_t)r * H + c]);
    atomicAdd(&pool[(size_t)g * POOL_W + layer * 256 + c], s0 + s1 + s2 + s3);
}

// ---------------------------------------------------------------------------
// FC head v2 (measured win in R4; unchanged): (64 x 12) blocks, lane-parallel
// 768-dot per output + shfl_xor reduce; FC2 folded via per-wave atomicAdd.
// ---------------------------------------------------------------------------
__global__ __launch_bounds__(256) void fc_head(
    const float* __restrict__ pool, const int* __restrict__ start,
    const float* __restrict__ L1w, const float* __restrict__ L1b,
    const float* __restrict__ L2w, float* __restrict__ gsum)
{
    const int g = blockIdx.x;
    __shared__ float p[POOL_W];

    const float rc = 1.0f / fmaxf((float)(start[g + 1] - start[g]), 1.0f);
    for (int i = threadIdx.x; i < POOL_W; i += 256)
        p[i] = pool[(size_t)g * POOL_W + i] * rc;
    __syncthreads();

    const int wv = threadIdx.x >> 6, lane = threadIdx.x & 63;
    const float4* p4 = (const float4*)p;
    const float4 pa = p4[lane], pb = p4[lane + 64], pc = p4[lane + 128];

    const int ob = blockIdx.y * 64 + wv * 16;
    float part = 0.0f;
#pragma unroll 4
    for (int t = 0; t < 16; ++t) {
        const int o = ob + t;
        const float4* wr = (const float4*)(L1w + (size_t)o * POOL_W);
        const float4 a = wr[lane], b = wr[lane + 64], c = wr[lane + 128];
        float acc = a.x * pa.x + a.y * pa.y + a.z * pa.z + a.w * pa.w
                  + b.x * pb.x + b.y * pb.y + b.z * pb.z + b.w * pb.w
                  + c.x * pc.x + c.y * pc.y + c.z * pc.z + c.w * pc.w;
#pragma unroll
        for (int off = 32; off > 0; off >>= 1) acc += __shfl_xor(acc, off);
        if (lane == 0) part += fmaxf(acc + L1b[o], 0.0f) * L2w[o];
    }
    if (lane == 0) atomicAdd(&gsum[g], part);
}

__global__ __launch_bounds__(64) void sig_kernel(
    const float* __restrict__ gsum, const float* __restrict__ L2b,
    float* __restrict__ out)
{
    const int g = threadIdx.x;
    if (g < N_GRAPHS) out[g] = 1.0f / (1.0f + expf(-(gsum[g] + L2b[0])));
}

// ---------------------------------------------------------------------------
extern "C" void kernel_launch(void* const* d_in, const int* in_sizes, int n_in,
                              void* d_out, int out_size, void* d_ws, size_t ws_size,
                              hipStream_t stream)
{
    const float* x     = (const float*)d_in[0];
    const float* ea    = (const float*)d_in[1];
    const int*   src   = (const int*)d_in[2];
    const int*   dst   = (const int*)d_in[3];
    const int*   batch = (const int*)d_in[4];

    const float* We[3]; const float* be[3]; const float* Wa[3]; const float* ba[3];
    const float* gg[3]; const float* bt[3]; const float* Wb[3]; const float* bb[3];
    for (int l = 0; l < 3; ++l) {
        const int o = 5 + 8 * l;
        We[l] = (const float*)d_in[o + 0]; be[l] = (const float*)d_in[o + 1];
        Wa[l] = (const float*)d_in[o + 2]; ba[l] = (const float*)d_in[o + 3];
        gg[l] = (const float*)d_in[o + 4]; bt[l] = (const float*)d_in[o + 5];
        Wb[l] = (const float*)d_in[o + 6]; bb[l] = (const float*)d_in[o + 7];
    }
    const float* L1w = (const float*)d_in[29];
    const float* L1b = (const float*)d_in[30];
    const float* L2w = (const float*)d_in[31];
    const float* L2b = (const float*)d_in[32];

    // ---- workspace layout ----
    float* pool   = (float*)d_ws;                              // 64*768
    float* gsum   = pool + (size_t)N_GRAPHS * POOL_W;          // 64 (zeroed with pool)
    int*   deg    = (int*)(gsum + N_GRAPHS);                   // N
    int*   off    = deg + N_NODES;                             // N+1
    int*   cursor = off + N_NODES + 1;                         // N
    int*   start  = cursor + N_NODES;                          // 72
    int*   ssrc   = (int*)((((uintptr_t)(start + 72)) + 31) & ~(uintptr_t)31);   // E ints, CSR order
    unsigned short* eas = (unsigned short*)((((uintptr_t)(ssrc + N_EDGES)) + 31) & ~(uintptr_t)31); // [E,16] f16 CSR order
    unsigned short* xb = (unsigned short*)((((uintptr_t)(eas + (size_t)N_EDGES * 16)) + 31) & ~(uintptr_t)31);
    unsigned short* u  = xb + (size_t)M_PAD * DIN;             // [M_PAD,256] (layer1 uses 128)
    unsigned short* tT = u  + (size_t)M_PAD * H;               // [M_PAD,256] intermediate
    unsigned short* h1 = tT + (size_t)M_PAD * H;
    unsigned short* h2 = h1 + (size_t)M_PAD * H;
    unsigned short* h3 = h2 + (size_t)M_PAD * H;
    unsigned short* wbf[6];
    wbf[0] = h3 + (size_t)M_PAD * H;                           // Wa1 [256,128]
    wbf[1] = wbf[0] + H * DIN;
    for (int i = 2; i < 6; ++i) wbf[i] = wbf[i - 1] + H * H;
    unsigned short* weh[3];
    weh[0] = wbf[5] + H * H;                                   // We1 [128,16] f16
    weh[1] = weh[0] + DIN * 16;                                // We2 [256,16] f16
    weh[2] = weh[1] + H * 16;                                  // We3 [256,16] f16

    // batched converts + deg/pool+gsum zeroing in one launch (12 jobs)
    CvtJobs jobs;
    jobs.j[0]  = { x,       xb,                    N_NODES * DIN / 4,       0 };
    jobs.j[1]  = { Wa[0],   wbf[0],                H * DIN / 4,             0 };
    jobs.j[2]  = { Wb[0],   wbf[1],                H * H / 4,               0 };
    jobs.j[3]  = { Wa[1],   wbf[2],                H * H / 4,               0 };
    jobs.j[4]  = { Wb[1],   wbf[3],                H * H / 4,               0 };
    jobs.j[5]  = { Wa[2],   wbf[4],                H * H / 4,               0 };
    jobs.j[6]  = { Wb[2],   wbf[5],                H * H / 4,               0 };
    jobs.j[7]  = { nullptr, (unsigned short*)deg,  N_NODES * 4 / 8,         2 };  // zero N ints
    jobs.j[8]  = { nullptr, (unsigned short*)pool, (N_GRAPHS * POOL_W + N_GRAPHS) * 4 / 8, 2 }; // zero pool+gsum
    jobs.j[9]  = { We[0],   weh[0],                DIN * 16 / 4,            1 };
    jobs.j[10] = { We[1],   weh[1],                H * 16 / 4,              1 };
    jobs.j[11] = { We[2],   weh[2],                H * 16 / 4,              1 };
    cvt_all<<<dim3(320, 12), 256, 0, stream>>>(jobs);

    // CSR + graph boundaries; scatter builds CSR-sorted (src, ea_f16)
    hist_kernel<<<(N_EDGES + 255) / 256, 256, 0, stream>>>(dst, deg);
    scan_kernel<<<1, 1024, 0, stream>>>(deg, off, cursor, batch, start);
    scatter_kernel<<<(N_EDGES + 255) / 256, 256, 0, stream>>>(src, dst, ea, cursor, ssrc, eas);

    const int  agrid = (N_NODES + 3) / 4;       // agg3: 1 node/wave
    const dim3 ggrid(M_PAD / 64, 2);            // (313, 2)

    // ---- layer 1 (in=128) ----
    agg3<DIN><<<agrid, 256, 0, stream>>>(xb, eas, ssrc, off, weh[0], be[0], u);
    gemm_breg2<DIN, 0><<<ggrid, 256, 0, stream>>>(u, wbf[0], ba[0], gg[0], bt[0], tT);
    gemm_breg2<H,   1><<<ggrid, 256, 0, stream>>>(tT, wbf[1], bb[0], nullptr, nullptr, h1);
    // ---- layer 2 ----
    agg3<H><<<agrid, 256, 0, stream>>>(h1, eas, ssrc, off, weh[1], be[1], u);
    gemm_breg2<H, 0><<<ggrid, 256, 0, stream>>>(u, wbf[2], ba[1], gg[1], bt[1], tT);
    gemm_breg2<H, 1><<<ggrid, 256, 0, stream>>>(tT, wbf[3], bb[1], nullptr, nullptr, h2);
    // ---- layer 3 ----
    agg3<H><<<agrid, 256, 0, stream>>>(h2, eas, ssrc, off, weh[2], be[2], u);
    gemm_breg2<H, 0><<<ggrid, 256, 0, stream>>>(u, wbf[4], ba[2], gg[2], bt[2], tT);
    gemm_breg2<H, 1><<<ggrid, 256, 0, stream>>>(tT, wbf[5], bb[2], nullptr, nullptr, h3);

    // parallel mean-pool + head
    pool2<<<dim3(3 * N_GRAPHS, RSPLIT), 256, 0, stream>>>(h1, h2, h3, start, pool);
    fc_head<<<dim3(N_GRAPHS, POOL_W / 64), 256, 0, stream>>>(pool, start, L1w, L1b, L2w, gsum);
    sig_kernel<<<1, 64, 0, stream>>>(gsum, L2b, (float*)d_out);
}